// Round 1
// baseline (2008.316 us; speedup 1.0000x reference)
//
#include <hip/hip_runtime.h>
#include <hip/hip_bf16.h>
#include <cstdint>
#include <cstddef>

#define NN 16000
#define EE 256000
#define ETOT (EE + NN)
#define RREL 8
#define NHEAD 8
#define DOUT 64
#define HD 512
#define NEG 0.2f

typedef unsigned int u32;

// ---------- helpers ----------
__device__ inline unsigned short f2bf(float f) {
  u32 i = __float_as_uint(f);
  u32 r = (i + 0x7fff + ((i >> 16) & 1)) >> 16;  // RNE, finite values
  return (unsigned short)r;
}
__device__ inline void store4(float* p, float x, float y, float z, float w) {
  *(float4*)p = make_float4(x, y, z, w);
}
__device__ inline void store4(unsigned short* p, float x, float y, float z, float w) {
  ushort4 v; v.x = f2bf(x); v.y = f2bf(y); v.z = f2bf(z); v.w = f2bf(w);
  *(ushort4*)p = v;
}
__device__ inline float2 load2(const float* p) { return *(const float2*)p; }
__device__ inline float2 load2(const unsigned short* p) {
  u32 v = *(const u32*)p;
  float lo = __uint_as_float((v & 0xffffu) << 16);
  float hi = __uint_as_float(v & 0xffff0000u);
  return make_float2(lo, hi);
}

// ---------- preprocessing ----------
__global__ void k_max_et(const int* __restrict__ et, int* meta) {
  int e = blockIdx.x * 256 + threadIdx.x;
  if (e < EE) atomicMax(&meta[0], et[e]);
}

__global__ void k_hist(const int* __restrict__ ei, int* __restrict__ deg) {
  int e = blockIdx.x * 256 + threadIdx.x;
  if (e >= ETOT) return;
  int dst = (e < EE) ? ei[EE + e] : (e - EE);
  atomicAdd(&deg[dst], 1);
}

__global__ __launch_bounds__(1024) void k_scan(const int* __restrict__ deg,
                                               int* __restrict__ rowptr,
                                               int* __restrict__ fill) {
  __shared__ int sm[1024];
  __shared__ int carry;
  if (threadIdx.x == 0) carry = 0;
  __syncthreads();
  for (int base = 0; base < NN; base += 1024) {
    int i = base + threadIdx.x;
    int v = (i < NN) ? deg[i] : 0;
    sm[threadIdx.x] = v;
    __syncthreads();
    for (int off = 1; off < 1024; off <<= 1) {
      int t = (threadIdx.x >= off) ? sm[threadIdx.x - off] : 0;
      __syncthreads();
      sm[threadIdx.x] += t;
      __syncthreads();
    }
    int incl = sm[threadIdx.x] + carry;
    if (i < NN) { rowptr[i] = incl - v; fill[i] = incl - v; }
    __syncthreads();
    if (threadIdx.x == 1023) carry = incl;
    __syncthreads();
  }
  if (threadIdx.x == 0) rowptr[NN] = carry;
}

__global__ void k_scatter(const int* __restrict__ ei, const int* __restrict__ et,
                          const float* __restrict__ ea, const int* __restrict__ meta,
                          int* __restrict__ fill, int* __restrict__ csr_src,
                          int* __restrict__ csr_et, float* __restrict__ csr_ea) {
  int e = blockIdx.x * 256 + threadIdx.x;
  if (e >= ETOT) return;
  int src, dst, r; float a;
  if (e < EE) { src = ei[e]; dst = ei[EE + e]; r = et[e]; a = ea[e]; }
  else { src = dst = e - EE; r = (meta[0] + 1) & (RREL - 1); a = 0.5f; }
  int pos = atomicAdd(&fill[dst], 1);
  csr_src[pos] = src; csr_et[pos] = r; csr_ea[pos] = a;
}

// ---------- per-layer small precomputes ----------
__global__ void k_cvec(const float* __restrict__ We, const float* __restrict__ e,
                       float* __restrict__ cvec) {
  int j = threadIdx.x;
  if (j >= NHEAD) return;
  float acc = 0.f;
  for (int h = 0; h < HD; ++h) acc += We[h] * e[h * NHEAD + j];
  cvec[j] = acc;
}

// WQ[r,f,:] = W[r,f,:] @ q ; WK with k.  grid covers R*F*16 threads.
__global__ void k_wqk(const float* __restrict__ W, const float* __restrict__ q,
                      const float* __restrict__ k, float* __restrict__ WQ,
                      float* __restrict__ WK) {
  int g = blockIdx.x * 256 + threadIdx.x;
  int j = g & 15;
  int rf = g >> 4;  // r*F + f
  const float* wrow = W + (size_t)rf * HD;
  const float* qk = ((j < 8) ? q : k) + (j & 7);
  float acc = 0.f;
  for (int h = 0; h < HD; ++h) acc += wrow[h] * qk[(size_t)h * NHEAD];
  ((j < 8) ? WQ : WK)[(size_t)rf * NHEAD + (j & 7)] = acc;
}

// qn[r,n,:] = in[n,:] @ WQ[r] ; kn likewise.  grid covers R*N*16 threads.
__global__ void k_qk(const float* __restrict__ in, const float* __restrict__ WQ,
                     const float* __restrict__ WK, float* __restrict__ qn,
                     float* __restrict__ kn, int F) {
  long g = (long)blockIdx.x * 256 + threadIdx.x;
  int j = (int)(g & 15);
  long pair = g >> 4;
  int n = (int)(pair % NN);
  int r = (int)(pair / NN);
  const float* w = ((j < 8) ? WQ : WK) + ((size_t)r * F) * NHEAD + (j & 7);
  const float* xr = in + (size_t)n * F;
  float acc = 0.f;
  for (int f = 0; f < F; ++f) acc += xr[f] * w[(size_t)f * NHEAD];
  ((j < 8) ? qn : kn)[((size_t)r * NN + n) * NHEAD + (j & 7)] = acc;
}

// ---------- main GEMM: C[r] = A @ W[r],  A:[16000,F], W[r]:[F,512] ----------
template <typename TC>
__global__ __launch_bounds__(256) void k_gemm(const float* __restrict__ A,
                                              const float* __restrict__ Wall,
                                              TC* __restrict__ C, int F) {
  const int r = blockIdx.z;
  const float* B = Wall + (size_t)r * F * HD;
  TC* Cr = C + (size_t)r * NN * HD;
  const int m0 = blockIdx.x * 128;
  const int n0 = blockIdx.y * 128;
  __shared__ float As[16][132];
  __shared__ float Bs[16][132];
  const int tid = threadIdx.x;
  const int arow = tid >> 2;
  const int acol = (tid & 3) << 2;
  const int brow = tid >> 5;
  const int bcol = (tid & 31) << 2;
  const int tr = ((tid >> 4) & 15) << 2;
  const int tc = (tid & 15) << 2;
  float acc[8][8] = {};
  for (int k0 = 0; k0 < F; k0 += 16) {
    float4 a0 = *(const float4*)&A[(size_t)(m0 + arow) * F + k0 + acol];
    float4 a1 = *(const float4*)&A[(size_t)(m0 + arow + 64) * F + k0 + acol];
    float4 b0 = *(const float4*)&B[(size_t)(k0 + brow) * HD + n0 + bcol];
    float4 b1 = *(const float4*)&B[(size_t)(k0 + brow + 8) * HD + n0 + bcol];
    As[acol + 0][arow] = a0.x; As[acol + 1][arow] = a0.y;
    As[acol + 2][arow] = a0.z; As[acol + 3][arow] = a0.w;
    As[acol + 0][arow + 64] = a1.x; As[acol + 1][arow + 64] = a1.y;
    As[acol + 2][arow + 64] = a1.z; As[acol + 3][arow + 64] = a1.w;
    *(float4*)&Bs[brow][bcol] = b0;
    *(float4*)&Bs[brow + 8][bcol] = b1;
    __syncthreads();
#pragma unroll
    for (int k = 0; k < 16; ++k) {
      float a[8], b[8];
      *(float4*)(a) = *(const float4*)&As[k][tr];
      *(float4*)(a + 4) = *(const float4*)&As[k][tr + 64];
      *(float4*)(b) = *(const float4*)&Bs[k][tc];
      *(float4*)(b + 4) = *(const float4*)&Bs[k][tc + 64];
#pragma unroll
      for (int i = 0; i < 8; ++i)
#pragma unroll
        for (int j = 0; j < 8; ++j)
          acc[i][j] = fmaf(a[i], b[j], acc[i][j]);
    }
    __syncthreads();
  }
#pragma unroll
  for (int i = 0; i < 8; ++i) {
    int row = m0 + tr + ((i < 4) ? i : (60 + i));
    store4(&Cr[(size_t)row * HD + n0 + tc], acc[i][0], acc[i][1], acc[i][2], acc[i][3]);
    store4(&Cr[(size_t)row * HD + n0 + tc + 64], acc[i][4], acc[i][5], acc[i][6], acc[i][7]);
  }
}

// ---------- fused attention + aggregation, one block per dst node ----------
template <typename T, int CONCAT>
__global__ __launch_bounds__(256) void k_attn(const T* __restrict__ t,
    const float* __restrict__ qn, const float* __restrict__ kn,
    const float* __restrict__ cvec, const int* __restrict__ rowptr,
    const int* __restrict__ csr_src, const int* __restrict__ csr_et,
    const float* __restrict__ csr_ea, const float* __restrict__ bias,
    float* __restrict__ out) {
  const int n = blockIdx.x;
  const int tid = threadIdx.x;
  const int h = tid >> 5;  // head of elements 2*tid, 2*tid+1
  const int e0 = rowptr[n], e1 = rowptr[n + 1];
  const float ch = cvec[h];
  float m = -1e30f, l = 0.f, acc0 = 0.f, acc1 = 0.f;
  for (int e = e0; e < e1; ++e) {
    int s = csr_src[e];
    int r = csr_et[e];
    float a = csr_ea[e];
    float logit = qn[((size_t)r * NN + n) * NHEAD + h]
                + kn[((size_t)r * NN + s) * NHEAD + h] + a * ch;
    logit = (logit > 0.f) ? logit : NEG * logit;
    float mn = fmaxf(m, logit);
    float sc = __expf(m - mn);
    float p = __expf(logit - mn);
    float2 tv = load2(&t[((size_t)r * NN + s) * HD + 2 * tid]);
    l = l * sc + p;
    acc0 = acc0 * sc + p * tv.x;
    acc1 = acc1 * sc + p * tv.y;
    m = mn;
  }
  float inv = 1.f / (l + 1e-16f);
  float v0 = acc0 * inv, v1 = acc1 * inv;
  if (CONCAT) {
    float2 bb = *(const float2*)&bias[2 * tid];
    *(float2*)&out[(size_t)n * HD + 2 * tid] = make_float2(v0 + bb.x, v1 + bb.y);
  } else {
    __shared__ float sm[HD];
    sm[2 * tid] = v0; sm[2 * tid + 1] = v1;
    __syncthreads();
    if (tid < DOUT) {
      float s = 0.f;
#pragma unroll
      for (int hh = 0; hh < NHEAD; ++hh) s += sm[hh * DOUT + tid];
      out[(size_t)n * DOUT + tid] = s * 0.125f + bias[tid];
    }
  }
}

// ---------- launch ----------
template <typename TC>
static void run_pipeline(const float* x, const int* ei, const int* et, const float* ea,
                         const float* W1, const float* q1, const float* k1,
                         const float* We1, const float* e1, const float* b1,
                         const float* W2, const float* q2, const float* k2,
                         const float* We2, const float* e2, const float* b2,
                         float* out, float* hbuf, float* qn, float* kn, float* WQ,
                         float* WK, float* cvec, int* meta, int* deg, int* rowptr,
                         int* fill, int* csr_src, int* csr_et, float* csr_ea,
                         TC* t, hipStream_t stream) {
  (void)hipMemsetAsync(meta, 0, 4, stream);
  (void)hipMemsetAsync(deg, 0, (size_t)NN * 4, stream);
  k_max_et<<<EE / 256, 256, 0, stream>>>(et, meta);
  k_hist<<<(ETOT + 255) / 256, 256, 0, stream>>>(ei, deg);
  k_scan<<<1, 1024, 0, stream>>>(deg, rowptr, fill);
  k_scatter<<<(ETOT + 255) / 256, 256, 0, stream>>>(ei, et, ea, meta, fill,
                                                    csr_src, csr_et, csr_ea);
  dim3 ggrid(125, 4, RREL);
  // layer 1 (F=256)
  k_cvec<<<1, 64, 0, stream>>>(We1, e1, cvec);
  k_wqk<<<RREL * 256 * 16 / 256, 256, 0, stream>>>(W1, q1, k1, WQ, WK);
  k_gemm<TC><<<ggrid, 256, 0, stream>>>(x, W1, t, 256);
  k_qk<<<RREL * NN * 16 / 256, 256, 0, stream>>>(x, WQ, WK, qn, kn, 256);
  k_attn<TC, 1><<<NN, 256, 0, stream>>>(t, qn, kn, cvec, rowptr, csr_src, csr_et,
                                        csr_ea, b1, hbuf);
  // layer 2 (F=512)
  k_cvec<<<1, 64, 0, stream>>>(We2, e2, cvec);
  k_wqk<<<RREL * HD * 16 / 256, 256, 0, stream>>>(W2, q2, k2, WQ, WK);
  k_gemm<TC><<<ggrid, 256, 0, stream>>>(hbuf, W2, t, HD);
  k_qk<<<RREL * NN * 16 / 256, 256, 0, stream>>>(hbuf, WQ, WK, qn, kn, HD);
  k_attn<TC, 0><<<NN, 256, 0, stream>>>(t, qn, kn, cvec, rowptr, csr_src, csr_et,
                                        csr_ea, b2, out);
}

extern "C" void kernel_launch(void* const* d_in, const int* in_sizes, int n_in,
                              void* d_out, int out_size, void* d_ws, size_t ws_size,
                              hipStream_t stream) {
  const float* x   = (const float*)d_in[0];
  const int*   ei  = (const int*)d_in[1];
  const int*   et  = (const int*)d_in[2];
  const float* ea  = (const float*)d_in[3];
  const float* W1  = (const float*)d_in[4];
  const float* q1  = (const float*)d_in[5];
  const float* k1  = (const float*)d_in[6];
  const float* We1 = (const float*)d_in[7];
  const float* e1  = (const float*)d_in[8];
  const float* b1  = (const float*)d_in[9];
  const float* W2  = (const float*)d_in[10];
  const float* q2  = (const float*)d_in[11];
  const float* k2  = (const float*)d_in[12];
  const float* We2 = (const float*)d_in[13];
  const float* e2  = (const float*)d_in[14];
  const float* b2  = (const float*)d_in[15];
  float* out = (float*)d_out;

  char* w = (char*)d_ws;
  auto alloc = [&](size_t bytes) {
    char* p = w;
    w += (bytes + 255) & ~(size_t)255;
    return p;
  };
  float* hbuf   = (float*)alloc((size_t)NN * HD * 4);
  float* qn     = (float*)alloc((size_t)RREL * NN * NHEAD * 4);
  float* kn     = (float*)alloc((size_t)RREL * NN * NHEAD * 4);
  float* WQ     = (float*)alloc((size_t)RREL * HD * NHEAD * 4);
  float* WK     = (float*)alloc((size_t)RREL * HD * NHEAD * 4);
  float* cvec   = (float*)alloc(64);
  int*   meta   = (int*)alloc(64);
  int*   deg    = (int*)alloc((size_t)NN * 4);
  int*   rowptr = (int*)alloc((size_t)(NN + 1) * 4);
  int*   fill   = (int*)alloc((size_t)NN * 4);
  int*   csr_src= (int*)alloc((size_t)ETOT * 4);
  int*   csr_et = (int*)alloc((size_t)ETOT * 4);
  float* csr_ea = (float*)alloc((size_t)ETOT * 4);
  size_t used = (size_t)(w - (char*)d_ws);
  size_t t_elems = (size_t)RREL * NN * HD;

  if (used + t_elems * 4 <= ws_size) {
    float* t = (float*)w;
    run_pipeline<float>(x, ei, et, ea, W1, q1, k1, We1, e1, b1,
                        W2, q2, k2, We2, e2, b2, out, hbuf, qn, kn, WQ, WK, cvec,
                        meta, deg, rowptr, fill, csr_src, csr_et, csr_ea, t, stream);
  } else {
    unsigned short* t = (unsigned short*)w;
    run_pipeline<unsigned short>(x, ei, et, ea, W1, q1, k1, We1, e1, b1,
                                 W2, q2, k2, We2, e2, b2, out, hbuf, qn, kn, WQ, WK,
                                 cvec, meta, deg, rowptr, fill, csr_src, csr_et,
                                 csr_ea, t, stream);
  }
}

// Round 2
// 1558.615 us; speedup vs baseline: 1.2885x; 1.2885x over previous
//
#include <hip/hip_runtime.h>
#include <hip/hip_bf16.h>
#include <cstdint>
#include <cstddef>

#define NN 16000
#define EE 256000
#define ETOT (EE + NN)
#define RREL 8
#define NHEAD 8
#define DOUT 64
#define HD 512
#define NEG 0.2f

typedef unsigned int u32;

// ---------- helpers ----------
__device__ inline unsigned short f2bf(float f) {
  u32 i = __float_as_uint(f);
  u32 r = (i + 0x7fff + ((i >> 16) & 1)) >> 16;  // RNE, finite values
  return (unsigned short)r;
}
__device__ inline void store4(float* p, float x, float y, float z, float w) {
  *(float4*)p = make_float4(x, y, z, w);
}
__device__ inline void store4(unsigned short* p, float x, float y, float z, float w) {
  ushort4 v; v.x = f2bf(x); v.y = f2bf(y); v.z = f2bf(z); v.w = f2bf(w);
  *(ushort4*)p = v;
}
__device__ inline float2 load2(const float* p) { return *(const float2*)p; }
__device__ inline float2 load2(const unsigned short* p) {
  u32 v = *(const u32*)p;
  float lo = __uint_as_float((v & 0xffffu) << 16);
  float hi = __uint_as_float(v & 0xffff0000u);
  return make_float2(lo, hi);
}

// ---------- preprocessing ----------
__global__ void k_max_et(const int* __restrict__ et, int* meta) {
  int e = blockIdx.x * 256 + threadIdx.x;
  if (e < EE) atomicMax(&meta[0], et[e]);
}

__global__ void k_hist(const int* __restrict__ ei, int* __restrict__ deg) {
  int e = blockIdx.x * 256 + threadIdx.x;
  if (e >= ETOT) return;
  int dst = (e < EE) ? ei[EE + e] : (e - EE);
  atomicAdd(&deg[dst], 1);
}

__global__ __launch_bounds__(1024) void k_scan(const int* __restrict__ deg,
                                               int* __restrict__ rowptr,
                                               int* __restrict__ fill) {
  __shared__ int sm[1024];
  __shared__ int carry;
  if (threadIdx.x == 0) carry = 0;
  __syncthreads();
  for (int base = 0; base < NN; base += 1024) {
    int i = base + threadIdx.x;
    int v = (i < NN) ? deg[i] : 0;
    sm[threadIdx.x] = v;
    __syncthreads();
    for (int off = 1; off < 1024; off <<= 1) {
      int t = (threadIdx.x >= off) ? sm[threadIdx.x - off] : 0;
      __syncthreads();
      sm[threadIdx.x] += t;
      __syncthreads();
    }
    int incl = sm[threadIdx.x] + carry;
    if (i < NN) { rowptr[i] = incl - v; fill[i] = incl - v; }
    __syncthreads();
    if (threadIdx.x == 1023) carry = incl;
    __syncthreads();
  }
  if (threadIdx.x == 0) rowptr[NN] = carry;
}

__global__ void k_scatter(const int* __restrict__ ei, const int* __restrict__ et,
                          const float* __restrict__ ea, const int* __restrict__ meta,
                          int* __restrict__ fill, int* __restrict__ csr_src,
                          int* __restrict__ csr_et, float* __restrict__ csr_ea) {
  int e = blockIdx.x * 256 + threadIdx.x;
  if (e >= ETOT) return;
  int src, dst, r; float a;
  if (e < EE) { src = ei[e]; dst = ei[EE + e]; r = et[e]; a = ea[e]; }
  else { src = dst = e - EE; r = (meta[0] + 1) & (RREL - 1); a = 0.5f; }
  int pos = atomicAdd(&fill[dst], 1);
  csr_src[pos] = src; csr_et[pos] = r; csr_ea[pos] = a;
}

// ---------- per-layer small precomputes ----------
__global__ void k_cvec(const float* __restrict__ We, const float* __restrict__ e,
                       float* __restrict__ cvec) {
  int j = threadIdx.x;
  if (j >= NHEAD) return;
  float acc = 0.f;
  for (int h = 0; h < HD; ++h) acc += We[h] * e[h * NHEAD + j];
  cvec[j] = acc;
}

// WQK[f, r*16 + j] : j<8 -> W[r,f,:]@q[:,j] ; j>=8 -> W[r,f,:]@k[:,j-8]
__global__ void k_wqk(const float* __restrict__ W, const float* __restrict__ q,
                      const float* __restrict__ k, float* __restrict__ WQK, int F) {
  int g = blockIdx.x * 256 + threadIdx.x;
  int j = g & 15;
  int rf = g >> 4;  // r*F + f
  int r = rf / F, f = rf % F;
  const float* wrow = W + (size_t)rf * HD;
  const float* qk = ((j < 8) ? q : k) + (j & 7);
  float acc = 0.f;
  for (int h = 0; h < HD; ++h) acc += wrow[h] * qk[(size_t)h * NHEAD];
  WQK[(size_t)f * 128 + r * 16 + j] = acc;
}

// ---------- tiled GEMM: C[z] = A @ B[z],  A:[16000,F], B[z]:[F,Nout] ----------
template <typename TC>
__global__ __launch_bounds__(256) void k_gemm(const float* __restrict__ A,
                                              const float* __restrict__ Ball,
                                              TC* __restrict__ C, int F, int ldb,
                                              long bstride, int ldc, long cstride) {
  const float* B = Ball + (size_t)blockIdx.z * bstride;
  TC* Cr = C + (size_t)blockIdx.z * cstride;
  const int m0 = blockIdx.x * 128;
  const int n0 = blockIdx.y * 128;
  __shared__ float As[16][132];
  __shared__ float Bs[16][132];
  const int tid = threadIdx.x;
  const int arow = tid >> 2;
  const int acol = (tid & 3) << 2;
  const int brow = tid >> 5;
  const int bcol = (tid & 31) << 2;
  const int tr = ((tid >> 4) & 15) << 2;
  const int tc = (tid & 15) << 2;
  float acc[8][8] = {};
  for (int k0 = 0; k0 < F; k0 += 16) {
    float4 a0 = *(const float4*)&A[(size_t)(m0 + arow) * F + k0 + acol];
    float4 a1 = *(const float4*)&A[(size_t)(m0 + arow + 64) * F + k0 + acol];
    float4 b0 = *(const float4*)&B[(size_t)(k0 + brow) * ldb + n0 + bcol];
    float4 b1 = *(const float4*)&B[(size_t)(k0 + brow + 8) * ldb + n0 + bcol];
    As[acol + 0][arow] = a0.x; As[acol + 1][arow] = a0.y;
    As[acol + 2][arow] = a0.z; As[acol + 3][arow] = a0.w;
    As[acol + 0][arow + 64] = a1.x; As[acol + 1][arow + 64] = a1.y;
    As[acol + 2][arow + 64] = a1.z; As[acol + 3][arow + 64] = a1.w;
    *(float4*)&Bs[brow][bcol] = b0;
    *(float4*)&Bs[brow + 8][bcol] = b1;
    __syncthreads();
#pragma unroll
    for (int k = 0; k < 16; ++k) {
      float a[8], b[8];
      *(float4*)(a) = *(const float4*)&As[k][tr];
      *(float4*)(a + 4) = *(const float4*)&As[k][tr + 64];
      *(float4*)(b) = *(const float4*)&Bs[k][tc];
      *(float4*)(b + 4) = *(const float4*)&Bs[k][tc + 64];
#pragma unroll
      for (int i = 0; i < 8; ++i)
#pragma unroll
        for (int j = 0; j < 8; ++j)
          acc[i][j] = fmaf(a[i], b[j], acc[i][j]);
    }
    __syncthreads();
  }
#pragma unroll
  for (int i = 0; i < 8; ++i) {
    int row = m0 + tr + ((i < 4) ? i : (60 + i));
    store4(&Cr[(size_t)row * ldc + n0 + tc], acc[i][0], acc[i][1], acc[i][2], acc[i][3]);
    store4(&Cr[(size_t)row * ldc + n0 + tc + 64], acc[i][4], acc[i][5], acc[i][6], acc[i][7]);
  }
}

// ---------- fused attention + aggregation, one block per dst node ----------
// qkbuf[n, r*16 + h]      = q-logit of node n under relation r, head h
// qkbuf[n, r*16 + 8 + h]  = k-logit
template <typename T, int CONCAT>
__global__ __launch_bounds__(256) void k_attn(const T* __restrict__ t,
    const float* __restrict__ qkbuf, const float* __restrict__ cvec,
    const int* __restrict__ rowptr, const int* __restrict__ csr_src,
    const int* __restrict__ csr_et, const float* __restrict__ csr_ea,
    const float* __restrict__ bias, float* __restrict__ out) {
  const int n = blockIdx.x;
  const int tid = threadIdx.x;
  const int h = tid >> 5;  // head of elements 2*tid, 2*tid+1
  const int e0 = rowptr[n], e1 = rowptr[n + 1];
  const float ch = cvec[h];
  const float* qrow = qkbuf + (size_t)n * 128;
  float m = -1e30f, l = 0.f, acc0 = 0.f, acc1 = 0.f;
  for (int e = e0; e < e1; ++e) {
    int s = csr_src[e];
    int r = csr_et[e];
    float a = csr_ea[e];
    float logit = qrow[r * 16 + h]
                + qkbuf[(size_t)s * 128 + r * 16 + 8 + h] + a * ch;
    logit = (logit > 0.f) ? logit : NEG * logit;
    float mn = fmaxf(m, logit);
    float sc = __expf(m - mn);
    float p = __expf(logit - mn);
    float2 tv = load2(&t[((size_t)r * NN + s) * HD + 2 * tid]);
    l = l * sc + p;
    acc0 = acc0 * sc + p * tv.x;
    acc1 = acc1 * sc + p * tv.y;
    m = mn;
  }
  float inv = 1.f / (l + 1e-16f);
  float v0 = acc0 * inv, v1 = acc1 * inv;
  if (CONCAT) {
    float2 bb = *(const float2*)&bias[2 * tid];
    *(float2*)&out[(size_t)n * HD + 2 * tid] = make_float2(v0 + bb.x, v1 + bb.y);
  } else {
    __shared__ float sm[HD];
    sm[2 * tid] = v0; sm[2 * tid + 1] = v1;
    __syncthreads();
    if (tid < DOUT) {
      float s = 0.f;
#pragma unroll
      for (int hh = 0; hh < NHEAD; ++hh) s += sm[hh * DOUT + tid];
      out[(size_t)n * DOUT + tid] = s * 0.125f + bias[tid];
    }
  }
}

// ---------- launch ----------
template <typename TC>
static void run_pipeline(const float* x, const int* ei, const int* et, const float* ea,
                         const float* W1, const float* q1, const float* k1,
                         const float* We1, const float* e1, const float* b1,
                         const float* W2, const float* q2, const float* k2,
                         const float* We2, const float* e2, const float* b2,
                         float* out, float* hbuf, float* qkbuf, float* WQK,
                         float* cvec, int* meta, int* deg, int* rowptr,
                         int* fill, int* csr_src, int* csr_et, float* csr_ea,
                         TC* t, hipStream_t stream) {
  (void)hipMemsetAsync(meta, 0, 4, stream);
  (void)hipMemsetAsync(deg, 0, (size_t)NN * 4, stream);
  k_max_et<<<EE / 256, 256, 0, stream>>>(et, meta);
  k_hist<<<(ETOT + 255) / 256, 256, 0, stream>>>(ei, deg);
  k_scan<<<1, 1024, 0, stream>>>(deg, rowptr, fill);
  k_scatter<<<(ETOT + 255) / 256, 256, 0, stream>>>(ei, et, ea, meta, fill,
                                                    csr_src, csr_et, csr_ea);
  dim3 ggrid(125, 4, RREL);
  dim3 qgrid(125, 1, 1);
  // layer 1 (F=256)
  k_cvec<<<1, 64, 0, stream>>>(We1, e1, cvec);
  k_wqk<<<RREL * 256 * 16 / 256, 256, 0, stream>>>(W1, q1, k1, WQK, 256);
  k_gemm<TC><<<ggrid, 256, 0, stream>>>(x, W1, t, 256, HD, (long)256 * HD,
                                        HD, (long)NN * HD);
  k_gemm<float><<<qgrid, 256, 0, stream>>>(x, WQK, qkbuf, 256, 128, 0, 128, 0);
  k_attn<TC, 1><<<NN, 256, 0, stream>>>(t, qkbuf, cvec, rowptr, csr_src, csr_et,
                                        csr_ea, b1, hbuf);
  // layer 2 (F=512)
  k_cvec<<<1, 64, 0, stream>>>(We2, e2, cvec);
  k_wqk<<<RREL * HD * 16 / 256, 256, 0, stream>>>(W2, q2, k2, WQK, HD);
  k_gemm<TC><<<ggrid, 256, 0, stream>>>(hbuf, W2, t, HD, HD, (long)HD * HD,
                                        HD, (long)NN * HD);
  k_gemm<float><<<qgrid, 256, 0, stream>>>(hbuf, WQK, qkbuf, HD, 128, 0, 128, 0);
  k_attn<TC, 0><<<NN, 256, 0, stream>>>(t, qkbuf, cvec, rowptr, csr_src, csr_et,
                                        csr_ea, b2, out);
}

extern "C" void kernel_launch(void* const* d_in, const int* in_sizes, int n_in,
                              void* d_out, int out_size, void* d_ws, size_t ws_size,
                              hipStream_t stream) {
  const float* x   = (const float*)d_in[0];
  const int*   ei  = (const int*)d_in[1];
  const int*   et  = (const int*)d_in[2];
  const float* ea  = (const float*)d_in[3];
  const float* W1  = (const float*)d_in[4];
  const float* q1  = (const float*)d_in[5];
  const float* k1  = (const float*)d_in[6];
  const float* We1 = (const float*)d_in[7];
  const float* e1  = (const float*)d_in[8];
  const float* b1  = (const float*)d_in[9];
  const float* W2  = (const float*)d_in[10];
  const float* q2  = (const float*)d_in[11];
  const float* k2  = (const float*)d_in[12];
  const float* We2 = (const float*)d_in[13];
  const float* e2  = (const float*)d_in[14];
  const float* b2  = (const float*)d_in[15];
  float* out = (float*)d_out;

  char* w = (char*)d_ws;
  auto alloc = [&](size_t bytes) {
    char* p = w;
    w += (bytes + 255) & ~(size_t)255;
    return p;
  };
  float* hbuf   = (float*)alloc((size_t)NN * HD * 4);
  float* qkbuf  = (float*)alloc((size_t)NN * 128 * 4);
  float* WQK    = (float*)alloc((size_t)HD * 128 * 4);
  float* cvec   = (float*)alloc(64);
  int*   meta   = (int*)alloc(64);
  int*   deg    = (int*)alloc((size_t)NN * 4);
  int*   rowptr = (int*)alloc((size_t)(NN + 1) * 4);
  int*   fill   = (int*)alloc((size_t)NN * 4);
  int*   csr_src= (int*)alloc((size_t)ETOT * 4);
  int*   csr_et = (int*)alloc((size_t)ETOT * 4);
  float* csr_ea = (float*)alloc((size_t)ETOT * 4);
  size_t used = (size_t)(w - (char*)d_ws);
  size_t t_elems = (size_t)RREL * NN * HD;

  if (used + t_elems * 4 <= ws_size) {
    float* t = (float*)w;
    run_pipeline<float>(x, ei, et, ea, W1, q1, k1, We1, e1, b1,
                        W2, q2, k2, We2, e2, b2, out, hbuf, qkbuf, WQK, cvec,
                        meta, deg, rowptr, fill, csr_src, csr_et, csr_ea, t, stream);
  } else {
    unsigned short* t = (unsigned short*)w;
    run_pipeline<unsigned short>(x, ei, et, ea, W1, q1, k1, We1, e1, b1,
                                 W2, q2, k2, We2, e2, b2, out, hbuf, qkbuf, WQK,
                                 cvec, meta, deg, rowptr, fill, csr_src, csr_et,
                                 csr_ea, t, stream);
  }
}

// Round 3
// 1077.664 us; speedup vs baseline: 1.8636x; 1.4463x over previous
//
#include <hip/hip_runtime.h>
#include <hip/hip_bf16.h>
#include <cstdint>
#include <cstddef>

#define NN 16000
#define EE 256000
#define ETOT (EE + NN)
#define RREL 8
#define NHEAD 8
#define DOUT 64
#define HD 512
#define NEG 0.2f

typedef unsigned int u32;
typedef short bf16x8 __attribute__((ext_vector_type(8)));
typedef float f32x4 __attribute__((ext_vector_type(4)));

// ---------- helpers ----------
__device__ inline unsigned short f2bf(float f) {
  u32 i = __float_as_uint(f);
  u32 r = (i + 0x7fff + ((i >> 16) & 1)) >> 16;  // RNE, finite values
  return (unsigned short)r;
}
__device__ inline float bf2f(unsigned short h) {
  return __uint_as_float((u32)h << 16);
}
__device__ inline void storeC(float* p, float v) { *p = v; }
__device__ inline void storeC(unsigned short* p, float v) { *p = f2bf(v); }
__device__ inline float2 load2(const float* p) { return *(const float2*)p; }
__device__ inline float2 load2(const unsigned short* p) {
  u32 v = *(const u32*)p;
  float lo = __uint_as_float((v & 0xffffu) << 16);
  float hi = __uint_as_float(v & 0xffff0000u);
  return make_float2(lo, hi);
}
__device__ inline void g2lds16(const void* g, void* lds) {
  __builtin_amdgcn_global_load_lds(
      (const __attribute__((address_space(1))) unsigned int*)g,
      (__attribute__((address_space(3))) unsigned int*)lds, 16, 0, 0);
}

// ---------- preprocessing ----------
__global__ void k_max_et(const int* __restrict__ et, int* meta) {
  int e = blockIdx.x * 256 + threadIdx.x;
  if (e < EE) atomicMax(&meta[0], et[e]);
}

__global__ void k_hist(const int* __restrict__ ei, int* __restrict__ deg) {
  int e = blockIdx.x * 256 + threadIdx.x;
  if (e >= ETOT) return;
  int dst = (e < EE) ? ei[EE + e] : (e - EE);
  atomicAdd(&deg[dst], 1);
}

__global__ __launch_bounds__(1024) void k_scan(const int* __restrict__ deg,
                                               int* __restrict__ rowptr,
                                               int* __restrict__ fill) {
  __shared__ int sm[1024];
  __shared__ int carry;
  if (threadIdx.x == 0) carry = 0;
  __syncthreads();
  for (int base = 0; base < NN; base += 1024) {
    int i = base + threadIdx.x;
    int v = (i < NN) ? deg[i] : 0;
    sm[threadIdx.x] = v;
    __syncthreads();
    for (int off = 1; off < 1024; off <<= 1) {
      int t = (threadIdx.x >= off) ? sm[threadIdx.x - off] : 0;
      __syncthreads();
      sm[threadIdx.x] += t;
      __syncthreads();
    }
    int incl = sm[threadIdx.x] + carry;
    if (i < NN) { rowptr[i] = incl - v; fill[i] = incl - v; }
    __syncthreads();
    if (threadIdx.x == 1023) carry = incl;
    __syncthreads();
  }
  if (threadIdx.x == 0) rowptr[NN] = carry;
}

__global__ void k_scatter(const int* __restrict__ ei, const int* __restrict__ et,
                          const float* __restrict__ ea, const int* __restrict__ meta,
                          int* __restrict__ fill, int* __restrict__ csr_src,
                          int* __restrict__ csr_et, float* __restrict__ csr_ea) {
  int e = blockIdx.x * 256 + threadIdx.x;
  if (e >= ETOT) return;
  int src, dst, r; float a;
  if (e < EE) { src = ei[e]; dst = ei[EE + e]; r = et[e]; a = ea[e]; }
  else { src = dst = e - EE; r = (meta[0] + 1) & (RREL - 1); a = 0.5f; }
  int pos = atomicAdd(&fill[dst], 1);
  csr_src[pos] = src; csr_et[pos] = r; csr_ea[pos] = a;
}

// ---------- per-layer small precomputes ----------
__global__ void k_cvec(const float* __restrict__ We, const float* __restrict__ e,
                       float* __restrict__ cvec) {
  int j = threadIdx.x;
  if (j >= NHEAD) return;
  float acc = 0.f;
  for (int h = 0; h < HD; ++h) acc += We[h] * e[h * NHEAD + j];
  cvec[j] = acc;
}

// WQK[f, r*16 + j] : j<8 -> W[r,f,:]@q[:,j] ; j>=8 -> W[r,f,:]@k[:,j-8]
__global__ void k_wqk(const float* __restrict__ W, const float* __restrict__ q,
                      const float* __restrict__ k, float* __restrict__ WQK, int F) {
  int g = blockIdx.x * 256 + threadIdx.x;
  int j = g & 15;
  int rf = g >> 4;  // r*F + f
  int r = rf / F, f = rf % F;
  const float* wrow = W + (size_t)rf * HD;
  const float* qk = ((j < 8) ? q : k) + (j & 7);
  float acc = 0.f;
  for (int h = 0; h < HD; ++h) acc += wrow[h] * qk[(size_t)h * NHEAD];
  WQK[(size_t)f * 128 + r * 16 + j] = acc;
}

// ---------- split-bf16 operand builders ----------
// in: [NN][F] f32 -> A2: [NN][3F] bf16 = [hi | lo | hi]
__global__ void k_asplit(const float* __restrict__ in, unsigned short* __restrict__ A2,
                         int F) {
  long idx = (long)blockIdx.x * 256 + threadIdx.x;  // over NN * F/4
  long total = (long)NN * (F >> 2);
  if (idx >= total) return;
  int row = (int)(idx / (F >> 2));
  int c4 = (int)(idx % (F >> 2)) << 2;
  float4 v = *(const float4*)&in[(size_t)row * F + c4];
  ushort4 hi, lo;
  hi.x = f2bf(v.x); hi.y = f2bf(v.y); hi.z = f2bf(v.z); hi.w = f2bf(v.w);
  lo.x = f2bf(v.x - bf2f(hi.x)); lo.y = f2bf(v.y - bf2f(hi.y));
  lo.z = f2bf(v.z - bf2f(hi.z)); lo.w = f2bf(v.w - bf2f(hi.w));
  unsigned short* base = A2 + (size_t)row * 3 * F;
  *(ushort4*)&base[c4] = hi;
  *(ushort4*)&base[F + c4] = lo;
  *(ushort4*)&base[2 * F + c4] = hi;
}

// W: [R][F][512] f32 -> BT: [R][512][3F] bf16, BT[r][c][k'] = hi/hi/lo of W[r][k'%F][c]
__global__ __launch_bounds__(256) void k_bsplit(const float* __restrict__ W,
                                                unsigned short* __restrict__ BT, int F) {
  int f0 = blockIdx.x * 64, c0 = blockIdx.y * 64, r = blockIdx.z;
  __shared__ float tile[64][65];
  int tid = threadIdx.x;
  int i0 = tid >> 6;   // 0..3
  int j = tid & 63;
  const float* Wr = W + (size_t)r * F * 512;
  for (int i = i0; i < 64; i += 4)
    tile[i][j] = Wr[(size_t)(f0 + i) * 512 + c0 + j];
  __syncthreads();
  unsigned short* Br = BT + (size_t)r * 512 * 3 * F;
  for (int c = i0; c < 64; c += 4) {
    float v = tile[j][c];  // W[r][f0+j][c0+c]
    unsigned short hi = f2bf(v);
    unsigned short lo = f2bf(v - bf2f(hi));
    unsigned short* dst = Br + (size_t)(c0 + c) * 3 * F + f0 + j;
    dst[0] = hi; dst[F] = hi; dst[2 * F] = lo;
  }
}

// ---------- MFMA GEMM: C[r] = A2 @ B_cat[r]  (bf16 in, f32 acc) ----------
// A2: [NN][Kp] bf16 row-major; BT: [r][512][Kp] bf16 (col-major B);
// 128x128 tile, BK=32, 4 waves of 64x64, fragment-ordered LDS (conflict-free).
template <typename TC>
__global__ __launch_bounds__(256) void k_mgemm(const unsigned short* __restrict__ A2,
                                               const unsigned short* __restrict__ BT,
                                               TC* __restrict__ C, int Kp,
                                               long cstride) {
  const int r = blockIdx.z;
  const unsigned short* Br = BT + (size_t)r * 512 * Kp;
  TC* Cr = C + (size_t)r * cstride;
  const int m0 = blockIdx.x * 128;
  const int n0 = blockIdx.y * 128;
  __shared__ unsigned short Asm[2][4096];  // 8 fragment-groups * 512 shorts
  __shared__ unsigned short Bsm[2][4096];
  const int tid = threadIdx.x;
  const int wid = tid >> 6;
  const int lane = tid & 63;
  const int wr = wid >> 1, wc = wid & 1;
  const int rlow = lane & 15;
  const int kch = lane >> 4;  // k-chunk 0..3

  // per-lane global bases for the 16B fragment units this wave stages
  const unsigned short* gA0 = A2 + (size_t)(m0 + wid * 16 + rlow) * Kp + kch * 8;
  const unsigned short* gA1 = A2 + (size_t)(m0 + (wid + 4) * 16 + rlow) * Kp + kch * 8;
  const unsigned short* gB0 = Br + (size_t)(n0 + wid * 16 + rlow) * Kp + kch * 8;
  const unsigned short* gB1 = Br + (size_t)(n0 + (wid + 4) * 16 + rlow) * Kp + kch * 8;

  f32x4 acc[4][4] = {};
  const int nt = Kp >> 5;

  // prologue: stage tile 0 into buffer 0
  g2lds16(gA0, &Asm[0][wid * 512]);
  g2lds16(gA1, &Asm[0][(wid + 4) * 512]);
  g2lds16(gB0, &Bsm[0][wid * 512]);
  g2lds16(gB1, &Bsm[0][(wid + 4) * 512]);
  __syncthreads();

  for (int t = 0; t < nt; ++t) {
    const int cur = t & 1;
    if (t + 1 < nt) {
      const int k0 = (t + 1) << 5;
      g2lds16(gA0 + k0, &Asm[cur ^ 1][wid * 512]);
      g2lds16(gA1 + k0, &Asm[cur ^ 1][(wid + 4) * 512]);
      g2lds16(gB0 + k0, &Bsm[cur ^ 1][wid * 512]);
      g2lds16(gB1 + k0, &Bsm[cur ^ 1][(wid + 4) * 512]);
    }
    bf16x8 af[4], bfr[4];
#pragma unroll
    for (int i = 0; i < 4; ++i)
      af[i] = *(const bf16x8*)&Asm[cur][(wr * 4 + i) * 512 + lane * 8];
#pragma unroll
    for (int j = 0; j < 4; ++j)
      bfr[j] = *(const bf16x8*)&Bsm[cur][(wc * 4 + j) * 512 + lane * 8];
#pragma unroll
    for (int i = 0; i < 4; ++i)
#pragma unroll
      for (int j = 0; j < 4; ++j)
        acc[i][j] = __builtin_amdgcn_mfma_f32_16x16x32_bf16(af[i], bfr[j], acc[i][j],
                                                            0, 0, 0);
    __syncthreads();
  }

  // epilogue: C/D layout col=lane&15, row=(lane>>4)*4+q  (guide m89)
#pragma unroll
  for (int i = 0; i < 4; ++i) {
    const int row0 = m0 + wr * 64 + i * 16 + kch * 4;
#pragma unroll
    for (int j = 0; j < 4; ++j) {
      const int col = n0 + wc * 64 + j * 16 + rlow;
#pragma unroll
      for (int q = 0; q < 4; ++q)
        storeC(&Cr[(size_t)(row0 + q) * HD + col], acc[i][j][q]);
    }
  }
}

// ---------- small fp32 GEMM (for qkbuf): C = A @ B, B:[F][128] ----------
__global__ __launch_bounds__(256) void k_gemm(const float* __restrict__ A,
                                              const float* __restrict__ B,
                                              float* __restrict__ C, int F) {
  const int m0 = blockIdx.x * 128;
  __shared__ float As[16][132];
  __shared__ float Bs[16][132];
  const int tid = threadIdx.x;
  const int arow = tid >> 2;
  const int acol = (tid & 3) << 2;
  const int brow = tid >> 5;
  const int bcol = (tid & 31) << 2;
  const int tr = ((tid >> 4) & 15) << 2;
  const int tc = (tid & 15) << 2;
  float acc[8][8] = {};
  for (int k0 = 0; k0 < F; k0 += 16) {
    float4 a0 = *(const float4*)&A[(size_t)(m0 + arow) * F + k0 + acol];
    float4 a1 = *(const float4*)&A[(size_t)(m0 + arow + 64) * F + k0 + acol];
    float4 b0 = *(const float4*)&B[(size_t)(k0 + brow) * 128 + bcol];
    float4 b1 = *(const float4*)&B[(size_t)(k0 + brow + 8) * 128 + bcol];
    As[acol + 0][arow] = a0.x; As[acol + 1][arow] = a0.y;
    As[acol + 2][arow] = a0.z; As[acol + 3][arow] = a0.w;
    As[acol + 0][arow + 64] = a1.x; As[acol + 1][arow + 64] = a1.y;
    As[acol + 2][arow + 64] = a1.z; As[acol + 3][arow + 64] = a1.w;
    *(float4*)&Bs[brow][bcol] = b0;
    *(float4*)&Bs[brow + 8][bcol] = b1;
    __syncthreads();
#pragma unroll
    for (int k = 0; k < 16; ++k) {
      float a[8], b[8];
      *(float4*)(a) = *(const float4*)&As[k][tr];
      *(float4*)(a + 4) = *(const float4*)&As[k][tr + 64];
      *(float4*)(b) = *(const float4*)&Bs[k][tc];
      *(float4*)(b + 4) = *(const float4*)&Bs[k][tc + 64];
#pragma unroll
      for (int i = 0; i < 8; ++i)
#pragma unroll
        for (int j = 0; j < 8; ++j)
          acc[i][j] = fmaf(a[i], b[j], acc[i][j]);
    }
    __syncthreads();
  }
#pragma unroll
  for (int i = 0; i < 8; ++i) {
    int row = m0 + tr + ((i < 4) ? i : (60 + i));
    if (tc < 64) {
      *(float4*)&C[(size_t)row * 128 + tc] = make_float4(acc[i][0], acc[i][1], acc[i][2], acc[i][3]);
      *(float4*)&C[(size_t)row * 128 + tc + 64] = make_float4(acc[i][4], acc[i][5], acc[i][6], acc[i][7]);
    }
  }
}

// ---------- fused attention + aggregation, one block per dst node ----------
template <typename T, int CONCAT>
__global__ __launch_bounds__(256) void k_attn(const T* __restrict__ t,
    const float* __restrict__ qkbuf, const float* __restrict__ cvec,
    const int* __restrict__ rowptr, const int* __restrict__ csr_src,
    const int* __restrict__ csr_et, const float* __restrict__ csr_ea,
    const float* __restrict__ bias, float* __restrict__ out) {
  const int n = blockIdx.x;
  const int tid = threadIdx.x;
  const int h = tid >> 5;  // head of elements 2*tid, 2*tid+1
  const int e0 = rowptr[n], e1 = rowptr[n + 1];
  const float ch = cvec[h];
  const float* qrow = qkbuf + (size_t)n * 128;
  float m = -1e30f, l = 0.f, acc0 = 0.f, acc1 = 0.f;
  for (int e = e0; e < e1; ++e) {
    int s = csr_src[e];
    int r = csr_et[e];
    float a = csr_ea[e];
    float logit = qrow[r * 16 + h]
                + qkbuf[(size_t)s * 128 + r * 16 + 8 + h] + a * ch;
    logit = (logit > 0.f) ? logit : NEG * logit;
    float mn = fmaxf(m, logit);
    float sc = __expf(m - mn);
    float p = __expf(logit - mn);
    float2 tv = load2(&t[((size_t)r * NN + s) * HD + 2 * tid]);
    l = l * sc + p;
    acc0 = acc0 * sc + p * tv.x;
    acc1 = acc1 * sc + p * tv.y;
    m = mn;
  }
  float inv = 1.f / (l + 1e-16f);
  float v0 = acc0 * inv, v1 = acc1 * inv;
  if (CONCAT) {
    float2 bb = *(const float2*)&bias[2 * tid];
    *(float2*)&out[(size_t)n * HD + 2 * tid] = make_float2(v0 + bb.x, v1 + bb.y);
  } else {
    __shared__ float sm[HD];
    sm[2 * tid] = v0; sm[2 * tid + 1] = v1;
    __syncthreads();
    if (tid < DOUT) {
      float s = 0.f;
#pragma unroll
      for (int hh = 0; hh < NHEAD; ++hh) s += sm[hh * DOUT + tid];
      out[(size_t)n * DOUT + tid] = s * 0.125f + bias[tid];
    }
  }
}

// ---------- launch ----------
template <typename TC>
static void run_pipeline(const float* x, const int* ei, const int* et, const float* ea,
                         const float* W1, const float* q1, const float* k1,
                         const float* We1, const float* e1, const float* b1,
                         const float* W2, const float* q2, const float* k2,
                         const float* We2, const float* e2, const float* b2,
                         float* out, float* hbuf, float* qkbuf, float* WQK,
                         unsigned short* A2, unsigned short* BT,
                         float* cvec, int* meta, int* deg, int* rowptr,
                         int* fill, int* csr_src, int* csr_et, float* csr_ea,
                         TC* t, hipStream_t stream) {
  (void)hipMemsetAsync(meta, 0, 4, stream);
  (void)hipMemsetAsync(deg, 0, (size_t)NN * 4, stream);
  k_max_et<<<EE / 256, 256, 0, stream>>>(et, meta);
  k_hist<<<(ETOT + 255) / 256, 256, 0, stream>>>(ei, deg);
  k_scan<<<1, 1024, 0, stream>>>(deg, rowptr, fill);
  k_scatter<<<(ETOT + 255) / 256, 256, 0, stream>>>(ei, et, ea, meta, fill,
                                                    csr_src, csr_et, csr_ea);
  dim3 mgrid(125, 4, RREL);
  // layer 1 (F=256, Kp=768)
  k_cvec<<<1, 64, 0, stream>>>(We1, e1, cvec);
  k_wqk<<<RREL * 256 * 16 / 256, 256, 0, stream>>>(W1, q1, k1, WQK, 256);
  k_asplit<<<(NN * 64 + 255) / 256, 256, 0, stream>>>(x, A2, 256);
  k_bsplit<<<dim3(4, 8, RREL), 256, 0, stream>>>(W1, BT, 256);
  k_mgemm<TC><<<mgrid, 256, 0, stream>>>(A2, BT, t, 768, (long)NN * HD);
  k_gemm<<<125, 256, 0, stream>>>(x, WQK, qkbuf, 256);
  k_attn<TC, 1><<<NN, 256, 0, stream>>>(t, qkbuf, cvec, rowptr, csr_src, csr_et,
                                        csr_ea, b1, hbuf);
  // layer 2 (F=512, Kp=1536)
  k_cvec<<<1, 64, 0, stream>>>(We2, e2, cvec);
  k_wqk<<<RREL * HD * 16 / 256, 256, 0, stream>>>(W2, q2, k2, WQK, HD);
  k_asplit<<<(NN * 128 + 255) / 256, 256, 0, stream>>>(hbuf, A2, HD);
  k_bsplit<<<dim3(8, 8, RREL), 256, 0, stream>>>(W2, BT, HD);
  k_mgemm<TC><<<mgrid, 256, 0, stream>>>(A2, BT, t, 1536, (long)NN * HD);
  k_gemm<<<125, 256, 0, stream>>>(hbuf, WQK, qkbuf, HD);
  k_attn<TC, 0><<<NN, 256, 0, stream>>>(t, qkbuf, cvec, rowptr, csr_src, csr_et,
                                        csr_ea, b2, out);
}

extern "C" void kernel_launch(void* const* d_in, const int* in_sizes, int n_in,
                              void* d_out, int out_size, void* d_ws, size_t ws_size,
                              hipStream_t stream) {
  const float* x   = (const float*)d_in[0];
  const int*   ei  = (const int*)d_in[1];
  const int*   et  = (const int*)d_in[2];
  const float* ea  = (const float*)d_in[3];
  const float* W1  = (const float*)d_in[4];
  const float* q1  = (const float*)d_in[5];
  const float* k1  = (const float*)d_in[6];
  const float* We1 = (const float*)d_in[7];
  const float* e1  = (const float*)d_in[8];
  const float* b1  = (const float*)d_in[9];
  const float* W2  = (const float*)d_in[10];
  const float* q2  = (const float*)d_in[11];
  const float* k2  = (const float*)d_in[12];
  const float* We2 = (const float*)d_in[13];
  const float* e2  = (const float*)d_in[14];
  const float* b2  = (const float*)d_in[15];
  float* out = (float*)d_out;

  char* w = (char*)d_ws;
  auto alloc = [&](size_t bytes) {
    char* p = w;
    w += (bytes + 255) & ~(size_t)255;
    return p;
  };
  float* hbuf   = (float*)alloc((size_t)NN * HD * 4);
  float* qkbuf  = (float*)alloc((size_t)NN * 128 * 4);
  float* WQK    = (float*)alloc((size_t)HD * 128 * 4);
  unsigned short* A2 = (unsigned short*)alloc((size_t)NN * 3 * HD * 2);
  unsigned short* BT = (unsigned short*)alloc((size_t)RREL * HD * 3 * HD * 2);
  float* cvec   = (float*)alloc(64);
  int*   meta   = (int*)alloc(64);
  int*   deg    = (int*)alloc((size_t)NN * 4);
  int*   rowptr = (int*)alloc((size_t)(NN + 1) * 4);
  int*   fill   = (int*)alloc((size_t)NN * 4);
  int*   csr_src= (int*)alloc((size_t)ETOT * 4);
  int*   csr_et = (int*)alloc((size_t)ETOT * 4);
  float* csr_ea = (float*)alloc((size_t)ETOT * 4);
  size_t used = (size_t)(w - (char*)d_ws);
  size_t t_elems = (size_t)RREL * NN * HD;

  if (used + t_elems * 4 <= ws_size) {
    float* t = (float*)w;
    run_pipeline<float>(x, ei, et, ea, W1, q1, k1, We1, e1, b1,
                        W2, q2, k2, We2, e2, b2, out, hbuf, qkbuf, WQK, A2, BT,
                        cvec, meta, deg, rowptr, fill, csr_src, csr_et, csr_ea,
                        t, stream);
  } else {
    unsigned short* t = (unsigned short*)w;
    run_pipeline<unsigned short>(x, ei, et, ea, W1, q1, k1, We1, e1, b1,
                                 W2, q2, k2, We2, e2, b2, out, hbuf, qkbuf, WQK,
                                 A2, BT, cvec, meta, deg, rowptr, fill, csr_src,
                                 csr_et, csr_ea, t, stream);
  }
}

// Round 4
// 1052.986 us; speedup vs baseline: 1.9073x; 1.0234x over previous
//
#include <hip/hip_runtime.h>
#include <hip/hip_bf16.h>
#include <cstdint>
#include <cstddef>

#define NN 16000
#define EE 256000
#define ETOT (EE + NN)
#define RREL 8
#define NHEAD 8
#define DOUT 64
#define HD 512
#define NEG 0.2f

typedef unsigned int u32;
typedef short bf16x8 __attribute__((ext_vector_type(8)));
typedef float f32x4 __attribute__((ext_vector_type(4)));

// ---------- helpers ----------
__device__ inline unsigned short f2bf(float f) {
  u32 i = __float_as_uint(f);
  u32 r = (i + 0x7fff + ((i >> 16) & 1)) >> 16;  // RNE, finite values
  return (unsigned short)r;
}
__device__ inline float bf2f(unsigned short h) {
  return __uint_as_float((u32)h << 16);
}
__device__ inline void storeC(float* p, float v) { *p = v; }
__device__ inline void storeC(unsigned short* p, float v) { *p = f2bf(v); }
__device__ inline float2 load2(const float* p) { return *(const float2*)p; }
__device__ inline float2 load2(const unsigned short* p) {
  u32 v = *(const u32*)p;
  float lo = __uint_as_float((v & 0xffffu) << 16);
  float hi = __uint_as_float(v & 0xffff0000u);
  return make_float2(lo, hi);
}
__device__ inline void g2lds16(const void* g, void* lds) {
  __builtin_amdgcn_global_load_lds(
      (const __attribute__((address_space(1))) unsigned int*)g,
      (__attribute__((address_space(3))) unsigned int*)lds, 16, 0, 0);
}

// ---------- preprocessing ----------
__global__ void k_max_et(const int* __restrict__ et, int* meta) {
  int e = blockIdx.x * 256 + threadIdx.x;
  if (e < EE) atomicMax(&meta[0], et[e]);
}

__global__ void k_hist(const int* __restrict__ ei, int* __restrict__ deg) {
  int e = blockIdx.x * 256 + threadIdx.x;
  if (e >= ETOT) return;
  int dst = (e < EE) ? ei[EE + e] : (e - EE);
  atomicAdd(&deg[dst], 1);
}

__global__ __launch_bounds__(1024) void k_scan(const int* __restrict__ deg,
                                               int* __restrict__ rowptr,
                                               int* __restrict__ fill) {
  __shared__ int sm[1024];
  __shared__ int carry;
  if (threadIdx.x == 0) carry = 0;
  __syncthreads();
  for (int base = 0; base < NN; base += 1024) {
    int i = base + threadIdx.x;
    int v = (i < NN) ? deg[i] : 0;
    sm[threadIdx.x] = v;
    __syncthreads();
    for (int off = 1; off < 1024; off <<= 1) {
      int t = (threadIdx.x >= off) ? sm[threadIdx.x - off] : 0;
      __syncthreads();
      sm[threadIdx.x] += t;
      __syncthreads();
    }
    int incl = sm[threadIdx.x] + carry;
    if (i < NN) { rowptr[i] = incl - v; fill[i] = incl - v; }
    __syncthreads();
    if (threadIdx.x == 1023) carry = incl;
    __syncthreads();
  }
  if (threadIdx.x == 0) rowptr[NN] = carry;
}

__global__ void k_scatter(const int* __restrict__ ei, const int* __restrict__ et,
                          const float* __restrict__ ea, const int* __restrict__ meta,
                          int* __restrict__ fill, int* __restrict__ csr_src,
                          int* __restrict__ csr_et, float* __restrict__ csr_ea) {
  int e = blockIdx.x * 256 + threadIdx.x;
  if (e >= ETOT) return;
  int src, dst, r; float a;
  if (e < EE) { src = ei[e]; dst = ei[EE + e]; r = et[e]; a = ea[e]; }
  else { src = dst = e - EE; r = (meta[0] + 1) & (RREL - 1); a = 0.5f; }
  int pos = atomicAdd(&fill[dst], 1);
  csr_src[pos] = src; csr_et[pos] = r; csr_ea[pos] = a;
}

// ---------- per-layer small precomputes ----------
__global__ void k_cvec(const float* __restrict__ We, const float* __restrict__ e,
                       float* __restrict__ cvec) {
  int j = threadIdx.x;
  if (j >= NHEAD) return;
  float acc = 0.f;
  for (int h = 0; h < HD; ++h) acc += We[h] * e[h * NHEAD + j];
  cvec[j] = acc;
}

// WQK[f, r*16 + j] : j<8 -> W[r,f,:]@q[:,j] ; j>=8 -> W[r,f,:]@k[:,j-8]
__global__ void k_wqk(const float* __restrict__ W, const float* __restrict__ q,
                      const float* __restrict__ k, float* __restrict__ WQK, int F) {
  int g = blockIdx.x * 256 + threadIdx.x;
  int j = g & 15;
  int rf = g >> 4;  // r*F + f
  int r = rf / F, f = rf % F;
  const float* wrow = W + (size_t)rf * HD;
  const float* qk = ((j < 8) ? q : k) + (j & 7);
  float acc = 0.f;
  for (int h = 0; h < HD; ++h) acc += wrow[h] * qk[(size_t)h * NHEAD];
  WQK[(size_t)f * 128 + r * 16 + j] = acc;
}

// ---------- split-bf16 operand builders ----------
// in: [NN][F] f32 -> A2: [NN][3F] bf16 = [hi | lo | hi]
__global__ void k_asplit(const float* __restrict__ in, unsigned short* __restrict__ A2,
                         int F) {
  long idx = (long)blockIdx.x * 256 + threadIdx.x;  // over NN * F/4
  long total = (long)NN * (F >> 2);
  if (idx >= total) return;
  int row = (int)(idx / (F >> 2));
  int c4 = (int)(idx % (F >> 2)) << 2;
  float4 v = *(const float4*)&in[(size_t)row * F + c4];
  ushort4 hi, lo;
  hi.x = f2bf(v.x); hi.y = f2bf(v.y); hi.z = f2bf(v.z); hi.w = f2bf(v.w);
  lo.x = f2bf(v.x - bf2f(hi.x)); lo.y = f2bf(v.y - bf2f(hi.y));
  lo.z = f2bf(v.z - bf2f(hi.z)); lo.w = f2bf(v.w - bf2f(hi.w));
  unsigned short* base = A2 + (size_t)row * 3 * F;
  *(ushort4*)&base[c4] = hi;
  *(ushort4*)&base[F + c4] = lo;
  *(ushort4*)&base[2 * F + c4] = hi;
}

// W: [R][F][512] f32 -> BT: [R][512][3F] bf16, BT[r][c][k'] = hi/hi/lo of W[r][k'%F][c]
__global__ __launch_bounds__(256) void k_bsplit(const float* __restrict__ W,
                                                unsigned short* __restrict__ BT, int F) {
  int f0 = blockIdx.x * 64, c0 = blockIdx.y * 64, r = blockIdx.z;
  __shared__ float tile[64][65];
  int tid = threadIdx.x;
  int i0 = tid >> 6;   // 0..3
  int j = tid & 63;
  const float* Wr = W + (size_t)r * F * 512;
  for (int i = i0; i < 64; i += 4)
    tile[i][j] = Wr[(size_t)(f0 + i) * 512 + c0 + j];
  __syncthreads();
  unsigned short* Br = BT + (size_t)r * 512 * 3 * F;
  for (int c = i0; c < 64; c += 4) {
    float v = tile[j][c];  // W[r][f0+j][c0+c]
    unsigned short hi = f2bf(v);
    unsigned short lo = f2bf(v - bf2f(hi));
    unsigned short* dst = Br + (size_t)(c0 + c) * 3 * F + f0 + j;
    dst[0] = hi; dst[F] = hi; dst[2 * F] = lo;
  }
}

// ---------- MFMA GEMM: C[r] = A2 @ B_cat[r]  (bf16 in, f32 acc) ----------
// A2: [NN][Kp] bf16 row-major; BT: [r][512][Kp] bf16 (col-major B);
// 128x128 tile, BK=32, 4 waves of 64x64, fragment-ordered LDS (conflict-free).
// Grid: 4000 1-D blocks. XCD-chunked swizzle: each XCD owns a contiguous
// v-range; within it (n0,r) varies fastest so 32 consecutive blocks share one
// 128-row A panel (L2-resident), and each A panel is fetched by ONE xcd only.
template <typename TC>
__global__ __launch_bounds__(256) void k_mgemm(const unsigned short* __restrict__ A2,
                                               const unsigned short* __restrict__ BT,
                                               TC* __restrict__ C, int Kp,
                                               long cstride) {
  const int bid = blockIdx.x;
  const int xcd = bid & 7;
  const int v = xcd * 500 + (bid >> 3);   // 4000 = 8 * 500, bijective
  const int mb = v >> 5;                  // 0..124  (m-panel, slowest)
  const int nr = v & 31;                  // (n0, r) fastest
  const int n0 = (nr & 3) << 7;
  const int r = nr >> 2;

  const unsigned short* Br = BT + (size_t)r * 512 * Kp;
  TC* Cr = C + (size_t)r * cstride;
  const int m0 = mb * 128;
  __shared__ unsigned short Asm[2][4096];  // 8 fragment-groups * 512 shorts
  __shared__ unsigned short Bsm[2][4096];
  const int tid = threadIdx.x;
  const int wid = tid >> 6;
  const int lane = tid & 63;
  const int wr = wid >> 1, wc = wid & 1;
  const int rlow = lane & 15;
  const int kch = lane >> 4;  // k-chunk 0..3

  // per-lane global bases for the 16B fragment units this wave stages
  const unsigned short* gA0 = A2 + (size_t)(m0 + wid * 16 + rlow) * Kp + kch * 8;
  const unsigned short* gA1 = A2 + (size_t)(m0 + (wid + 4) * 16 + rlow) * Kp + kch * 8;
  const unsigned short* gB0 = Br + (size_t)(n0 + wid * 16 + rlow) * Kp + kch * 8;
  const unsigned short* gB1 = Br + (size_t)(n0 + (wid + 4) * 16 + rlow) * Kp + kch * 8;

  f32x4 acc[4][4] = {};
  const int nt = Kp >> 5;

  // prologue: stage tile 0 into buffer 0
  g2lds16(gA0, &Asm[0][wid * 512]);
  g2lds16(gA1, &Asm[0][(wid + 4) * 512]);
  g2lds16(gB0, &Bsm[0][wid * 512]);
  g2lds16(gB1, &Bsm[0][(wid + 4) * 512]);
  __syncthreads();

  for (int t = 0; t < nt; ++t) {
    const int cur = t & 1;
    if (t + 1 < nt) {
      const int k0 = (t + 1) << 5;
      g2lds16(gA0 + k0, &Asm[cur ^ 1][wid * 512]);
      g2lds16(gA1 + k0, &Asm[cur ^ 1][(wid + 4) * 512]);
      g2lds16(gB0 + k0, &Bsm[cur ^ 1][wid * 512]);
      g2lds16(gB1 + k0, &Bsm[cur ^ 1][(wid + 4) * 512]);
    }
    bf16x8 af[4], bfr[4];
#pragma unroll
    for (int i = 0; i < 4; ++i)
      af[i] = *(const bf16x8*)&Asm[cur][(wr * 4 + i) * 512 + lane * 8];
#pragma unroll
    for (int j = 0; j < 4; ++j)
      bfr[j] = *(const bf16x8*)&Bsm[cur][(wc * 4 + j) * 512 + lane * 8];
#pragma unroll
    for (int i = 0; i < 4; ++i)
#pragma unroll
      for (int j = 0; j < 4; ++j)
        acc[i][j] = __builtin_amdgcn_mfma_f32_16x16x32_bf16(af[i], bfr[j], acc[i][j],
                                                            0, 0, 0);
    __syncthreads();
  }

  // epilogue: C/D layout col=lane&15, row=(lane>>4)*4+q  (guide m89)
#pragma unroll
  for (int i = 0; i < 4; ++i) {
    const int row0 = m0 + wr * 64 + i * 16 + kch * 4;
#pragma unroll
    for (int j = 0; j < 4; ++j) {
      const int col = n0 + wc * 64 + j * 16 + rlow;
#pragma unroll
      for (int q = 0; q < 4; ++q)
        storeC(&Cr[(size_t)(row0 + q) * HD + col], acc[i][j][q]);
    }
  }
}

// ---------- small fp32 GEMM (for qkbuf): C = A @ B, B:[F][128] ----------
__global__ __launch_bounds__(256) void k_gemm(const float* __restrict__ A,
                                              const float* __restrict__ B,
                                              float* __restrict__ C, int F) {
  const int m0 = blockIdx.x * 128;
  __shared__ float As[16][132];
  __shared__ float Bs[16][132];
  const int tid = threadIdx.x;
  const int arow = tid >> 2;
  const int acol = (tid & 3) << 2;
  const int brow = tid >> 5;
  const int bcol = (tid & 31) << 2;
  const int tr = ((tid >> 4) & 15) << 2;
  const int tc = (tid & 15) << 2;
  float acc[8][8] = {};
  for (int k0 = 0; k0 < F; k0 += 16) {
    float4 a0 = *(const float4*)&A[(size_t)(m0 + arow) * F + k0 + acol];
    float4 a1 = *(const float4*)&A[(size_t)(m0 + arow + 64) * F + k0 + acol];
    float4 b0 = *(const float4*)&B[(size_t)(k0 + brow) * 128 + bcol];
    float4 b1 = *(const float4*)&B[(size_t)(k0 + brow + 8) * 128 + bcol];
    As[acol + 0][arow] = a0.x; As[acol + 1][arow] = a0.y;
    As[acol + 2][arow] = a0.z; As[acol + 3][arow] = a0.w;
    As[acol + 0][arow + 64] = a1.x; As[acol + 1][arow + 64] = a1.y;
    As[acol + 2][arow + 64] = a1.z; As[acol + 3][arow + 64] = a1.w;
    *(float4*)&Bs[brow][bcol] = b0;
    *(float4*)&Bs[brow + 8][bcol] = b1;
    __syncthreads();
#pragma unroll
    for (int k = 0; k < 16; ++k) {
      float a[8], b[8];
      *(float4*)(a) = *(const float4*)&As[k][tr];
      *(float4*)(a + 4) = *(const float4*)&As[k][tr + 64];
      *(float4*)(b) = *(const float4*)&Bs[k][tc];
      *(float4*)(b + 4) = *(const float4*)&Bs[k][tc + 64];
#pragma unroll
      for (int i = 0; i < 8; ++i)
#pragma unroll
        for (int j = 0; j < 8; ++j)
          acc[i][j] = fmaf(a[i], b[j], acc[i][j]);
    }
    __syncthreads();
  }
#pragma unroll
  for (int i = 0; i < 8; ++i) {
    int row = m0 + tr + ((i < 4) ? i : (60 + i));
    *(float4*)&C[(size_t)row * 128 + tc] = make_float4(acc[i][0], acc[i][1], acc[i][2], acc[i][3]);
    *(float4*)&C[(size_t)row * 128 + tc + 64] = make_float4(acc[i][4], acc[i][5], acc[i][6], acc[i][7]);
  }
}

// ---------- fused attention + aggregation, one block per dst node ----------
template <typename T, int CONCAT>
__global__ __launch_bounds__(256) void k_attn(const T* __restrict__ t,
    const float* __restrict__ qkbuf, const float* __restrict__ cvec,
    const int* __restrict__ rowptr, const int* __restrict__ csr_src,
    const int* __restrict__ csr_et, const float* __restrict__ csr_ea,
    const float* __restrict__ bias, float* __restrict__ out) {
  const int n = blockIdx.x;
  const int tid = threadIdx.x;
  const int h = tid >> 5;  // head of elements 2*tid, 2*tid+1
  const int e0 = rowptr[n], e1 = rowptr[n + 1];
  const float ch = cvec[h];
  const float* qrow = qkbuf + (size_t)n * 128;
  float m = -1e30f, l = 0.f, acc0 = 0.f, acc1 = 0.f;
  for (int e = e0; e < e1; ++e) {
    int s = csr_src[e];
    int r = csr_et[e];
    float a = csr_ea[e];
    float logit = qrow[r * 16 + h]
                + qkbuf[(size_t)s * 128 + r * 16 + 8 + h] + a * ch;
    logit = (logit > 0.f) ? logit : NEG * logit;
    float mn = fmaxf(m, logit);
    float sc = __expf(m - mn);
    float p = __expf(logit - mn);
    float2 tv = load2(&t[((size_t)r * NN + s) * HD + 2 * tid]);
    l = l * sc + p;
    acc0 = acc0 * sc + p * tv.x;
    acc1 = acc1 * sc + p * tv.y;
    m = mn;
  }
  float inv = 1.f / (l + 1e-16f);
  float v0 = acc0 * inv, v1 = acc1 * inv;
  if (CONCAT) {
    float2 bb = *(const float2*)&bias[2 * tid];
    *(float2*)&out[(size_t)n * HD + 2 * tid] = make_float2(v0 + bb.x, v1 + bb.y);
  } else {
    __shared__ float sm[HD];
    sm[2 * tid] = v0; sm[2 * tid + 1] = v1;
    __syncthreads();
    if (tid < DOUT) {
      float s = 0.f;
#pragma unroll
      for (int hh = 0; hh < NHEAD; ++hh) s += sm[hh * DOUT + tid];
      out[(size_t)n * DOUT + tid] = s * 0.125f + bias[tid];
    }
  }
}

// ---------- launch ----------
template <typename TC>
static void run_pipeline(const float* x, const int* ei, const int* et, const float* ea,
                         const float* W1, const float* q1, const float* k1,
                         const float* We1, const float* e1, const float* b1,
                         const float* W2, const float* q2, const float* k2,
                         const float* We2, const float* e2, const float* b2,
                         float* out, float* hbuf, float* qkbuf, float* WQK,
                         unsigned short* A2, unsigned short* BT,
                         float* cvec, int* meta, int* deg, int* rowptr,
                         int* fill, int* csr_src, int* csr_et, float* csr_ea,
                         TC* t, hipStream_t stream) {
  (void)hipMemsetAsync(meta, 0, 4, stream);
  (void)hipMemsetAsync(deg, 0, (size_t)NN * 4, stream);
  k_max_et<<<EE / 256, 256, 0, stream>>>(et, meta);
  k_hist<<<(ETOT + 255) / 256, 256, 0, stream>>>(ei, deg);
  k_scan<<<1, 1024, 0, stream>>>(deg, rowptr, fill);
  k_scatter<<<(ETOT + 255) / 256, 256, 0, stream>>>(ei, et, ea, meta, fill,
                                                    csr_src, csr_et, csr_ea);
  // layer 1 (F=256, Kp=768)
  k_cvec<<<1, 64, 0, stream>>>(We1, e1, cvec);
  k_wqk<<<RREL * 256 * 16 / 256, 256, 0, stream>>>(W1, q1, k1, WQK, 256);
  k_asplit<<<(NN * 64 + 255) / 256, 256, 0, stream>>>(x, A2, 256);
  k_bsplit<<<dim3(4, 8, RREL), 256, 0, stream>>>(W1, BT, 256);
  k_mgemm<TC><<<4000, 256, 0, stream>>>(A2, BT, t, 768, (long)NN * HD);
  k_gemm<<<125, 256, 0, stream>>>(x, WQK, qkbuf, 256);
  k_attn<TC, 1><<<NN, 256, 0, stream>>>(t, qkbuf, cvec, rowptr, csr_src, csr_et,
                                        csr_ea, b1, hbuf);
  // layer 2 (F=512, Kp=1536)
  k_cvec<<<1, 64, 0, stream>>>(We2, e2, cvec);
  k_wqk<<<RREL * HD * 16 / 256, 256, 0, stream>>>(W2, q2, k2, WQK, HD);
  k_asplit<<<(NN * 128 + 255) / 256, 256, 0, stream>>>(hbuf, A2, HD);
  k_bsplit<<<dim3(8, 8, RREL), 256, 0, stream>>>(W2, BT, HD);
  k_mgemm<TC><<<4000, 256, 0, stream>>>(A2, BT, t, 1536, (long)NN * HD);
  k_gemm<<<125, 256, 0, stream>>>(hbuf, WQK, qkbuf, HD);
  k_attn<TC, 0><<<NN, 256, 0, stream>>>(t, qkbuf, cvec, rowptr, csr_src, csr_et,
                                        csr_ea, b2, out);
}

extern "C" void kernel_launch(void* const* d_in, const int* in_sizes, int n_in,
                              void* d_out, int out_size, void* d_ws, size_t ws_size,
                              hipStream_t stream) {
  const float* x   = (const float*)d_in[0];
  const int*   ei  = (const int*)d_in[1];
  const int*   et  = (const int*)d_in[2];
  const float* ea  = (const float*)d_in[3];
  const float* W1  = (const float*)d_in[4];
  const float* q1  = (const float*)d_in[5];
  const float* k1  = (const float*)d_in[6];
  const float* We1 = (const float*)d_in[7];
  const float* e1  = (const float*)d_in[8];
  const float* b1  = (const float*)d_in[9];
  const float* W2  = (const float*)d_in[10];
  const float* q2  = (const float*)d_in[11];
  const float* k2  = (const float*)d_in[12];
  const float* We2 = (const float*)d_in[13];
  const float* e2  = (const float*)d_in[14];
  const float* b2  = (const float*)d_in[15];
  float* out = (float*)d_out;

  char* w = (char*)d_ws;
  auto alloc = [&](size_t bytes) {
    char* p = w;
    w += (bytes + 255) & ~(size_t)255;
    return p;
  };
  float* hbuf   = (float*)alloc((size_t)NN * HD * 4);
  float* qkbuf  = (float*)alloc((size_t)NN * 128 * 4);
  float* WQK    = (float*)alloc((size_t)HD * 128 * 4);
  unsigned short* A2 = (unsigned short*)alloc((size_t)NN * 3 * HD * 2);
  unsigned short* BT = (unsigned short*)alloc((size_t)RREL * HD * 3 * HD * 2);
  float* cvec   = (float*)alloc(64);
  int*   meta   = (int*)alloc(64);
  int*   deg    = (int*)alloc((size_t)NN * 4);
  int*   rowptr = (int*)alloc((size_t)(NN + 1) * 4);
  int*   fill   = (int*)alloc((size_t)NN * 4);
  int*   csr_src= (int*)alloc((size_t)ETOT * 4);
  int*   csr_et = (int*)alloc((size_t)ETOT * 4);
  float* csr_ea = (float*)alloc((size_t)ETOT * 4);
  size_t used = (size_t)(w - (char*)d_ws);
  size_t t_elems = (size_t)RREL * NN * HD;

  if (used + t_elems * 4 <= ws_size) {
    float* t = (float*)w;
    run_pipeline<float>(x, ei, et, ea, W1, q1, k1, We1, e1, b1,
                        W2, q2, k2, We2, e2, b2, out, hbuf, qkbuf, WQK, A2, BT,
                        cvec, meta, deg, rowptr, fill, csr_src, csr_et, csr_ea,
                        t, stream);
  } else {
    unsigned short* t = (unsigned short*)w;
    run_pipeline<unsigned short>(x, ei, et, ea, W1, q1, k1, We1, e1, b1,
                                 W2, q2, k2, We2, e2, b2, out, hbuf, qkbuf, WQK,
                                 A2, BT, cvec, meta, deg, rowptr, fill, csr_src,
                                 csr_et, csr_ea, t, stream);
  }
}

// Round 5
// 856.712 us; speedup vs baseline: 2.3442x; 1.2291x over previous
//
#include <hip/hip_runtime.h>
#include <hip/hip_bf16.h>
#include <cstdint>
#include <cstddef>

#define NN 16000
#define EE 256000
#define ETOT (EE + NN)
#define RREL 8
#define NHEAD 8
#define DOUT 64
#define HD 512
#define NEG 0.2f

typedef unsigned int u32;
typedef short bf16x8 __attribute__((ext_vector_type(8)));
typedef float f32x4 __attribute__((ext_vector_type(4)));

// ---------- helpers ----------
__device__ inline unsigned short f2bf(float f) {
  u32 i = __float_as_uint(f);
  u32 r = (i + 0x7fff + ((i >> 16) & 1)) >> 16;  // RNE, finite values
  return (unsigned short)r;
}
__device__ inline float bf2f(unsigned short h) {
  return __uint_as_float((u32)h << 16);
}
__device__ inline void storeC(float* p, float v) { *p = v; }
__device__ inline void storeC(unsigned short* p, float v) { *p = f2bf(v); }
__device__ inline float2 load2(const float* p) { return *(const float2*)p; }
__device__ inline float2 load2(const unsigned short* p) {
  u32 v = *(const u32*)p;
  float lo = __uint_as_float((v & 0xffffu) << 16);
  float hi = __uint_as_float(v & 0xffff0000u);
  return make_float2(lo, hi);
}
__device__ inline void g2lds16(const void* g, void* lds) {
  __builtin_amdgcn_global_load_lds(
      (const __attribute__((address_space(1))) unsigned int*)g,
      (__attribute__((address_space(3))) unsigned int*)lds, 16, 0, 0);
}

// ---------- preprocessing ----------
__global__ void k_max_et(const int* __restrict__ et, int* meta) {
  int e = blockIdx.x * 256 + threadIdx.x;
  if (e < EE) atomicMax(&meta[0], et[e]);
}

__global__ void k_hist(const int* __restrict__ ei, int* __restrict__ deg) {
  int e = blockIdx.x * 256 + threadIdx.x;
  if (e >= ETOT) return;
  int dst = (e < EE) ? ei[EE + e] : (e - EE);
  atomicAdd(&deg[dst], 1);
}

__global__ __launch_bounds__(1024) void k_scan(const int* __restrict__ deg,
                                               int* __restrict__ rowptr,
                                               int* __restrict__ fill) {
  __shared__ int sm[1024];
  __shared__ int carry;
  if (threadIdx.x == 0) carry = 0;
  __syncthreads();
  for (int base = 0; base < NN; base += 1024) {
    int i = base + threadIdx.x;
    int v = (i < NN) ? deg[i] : 0;
    sm[threadIdx.x] = v;
    __syncthreads();
    for (int off = 1; off < 1024; off <<= 1) {
      int t = (threadIdx.x >= off) ? sm[threadIdx.x - off] : 0;
      __syncthreads();
      sm[threadIdx.x] += t;
      __syncthreads();
    }
    int incl = sm[threadIdx.x] + carry;
    if (i < NN) { rowptr[i] = incl - v; fill[i] = incl - v; }
    __syncthreads();
    if (threadIdx.x == 1023) carry = incl;
    __syncthreads();
  }
  if (threadIdx.x == 0) rowptr[NN] = carry;
}

__global__ void k_scatter(const int* __restrict__ ei, const int* __restrict__ et,
                          const float* __restrict__ ea, const int* __restrict__ meta,
                          int* __restrict__ fill, int* __restrict__ csr_src,
                          int* __restrict__ csr_et, float* __restrict__ csr_ea) {
  int e = blockIdx.x * 256 + threadIdx.x;
  if (e >= ETOT) return;
  int src, dst, r; float a;
  if (e < EE) { src = ei[e]; dst = ei[EE + e]; r = et[e]; a = ea[e]; }
  else { src = dst = e - EE; r = (meta[0] + 1) & (RREL - 1); a = 0.5f; }
  int pos = atomicAdd(&fill[dst], 1);
  csr_src[pos] = src; csr_et[pos] = r; csr_ea[pos] = a;
}

// ---------- per-layer small precomputes ----------
__global__ void k_cvec(const float* __restrict__ We, const float* __restrict__ e,
                       float* __restrict__ cvec) {
  int j = threadIdx.x;
  if (j >= NHEAD) return;
  float acc = 0.f;
  for (int h = 0; h < HD; ++h) acc += We[h] * e[h * NHEAD + j];
  cvec[j] = acc;
}

// WQK[f, r*16 + j] : j<8 -> W[r,f,:]@q[:,j] ; j>=8 -> W[r,f,:]@k[:,j-8]
__global__ void k_wqk(const float* __restrict__ W, const float* __restrict__ q,
                      const float* __restrict__ k, float* __restrict__ WQK, int F) {
  int g = blockIdx.x * 256 + threadIdx.x;
  int j = g & 15;
  int rf = g >> 4;  // r*F + f
  int r = rf / F, f = rf % F;
  const float* wrow = W + (size_t)rf * HD;
  const float* qk = ((j < 8) ? q : k) + (j & 7);
  float acc = 0.f;
  for (int h = 0; h < HD; ++h) acc += wrow[h] * qk[(size_t)h * NHEAD];
  WQK[(size_t)f * 128 + r * 16 + j] = acc;
}

// ---------- split-bf16 operand builders (2-term: A=[hi|lo], B=[hi;hi]) ----
// in: [NN][F] f32 -> A2: [NN][2F] bf16 = [hi | lo]
__global__ void k_asplit(const float* __restrict__ in, unsigned short* __restrict__ A2,
                         int F) {
  long idx = (long)blockIdx.x * 256 + threadIdx.x;  // over NN * F/4
  long total = (long)NN * (F >> 2);
  if (idx >= total) return;
  int row = (int)(idx / (F >> 2));
  int c4 = (int)(idx % (F >> 2)) << 2;
  float4 v = *(const float4*)&in[(size_t)row * F + c4];
  ushort4 hi, lo;
  hi.x = f2bf(v.x); hi.y = f2bf(v.y); hi.z = f2bf(v.z); hi.w = f2bf(v.w);
  lo.x = f2bf(v.x - bf2f(hi.x)); lo.y = f2bf(v.y - bf2f(hi.y));
  lo.z = f2bf(v.z - bf2f(hi.z)); lo.w = f2bf(v.w - bf2f(hi.w));
  unsigned short* base = A2 + (size_t)row * 2 * F;
  *(ushort4*)&base[c4] = hi;
  *(ushort4*)&base[F + c4] = lo;
}

// W: [R][F][512] f32 -> BT: [R][512][2F] bf16, BT[r][c][k'] = hi of W[r][k'%F][c]
__global__ __launch_bounds__(256) void k_bsplit(const float* __restrict__ W,
                                                unsigned short* __restrict__ BT, int F) {
  int f0 = blockIdx.x * 64, c0 = blockIdx.y * 64, r = blockIdx.z;
  __shared__ float tile[64][65];
  int tid = threadIdx.x;
  int i0 = tid >> 6;   // 0..3
  int j = tid & 63;
  const float* Wr = W + (size_t)r * F * 512;
  for (int i = i0; i < 64; i += 4)
    tile[i][j] = Wr[(size_t)(f0 + i) * 512 + c0 + j];
  __syncthreads();
  unsigned short* Br = BT + (size_t)r * 512 * 2 * F;
  for (int c = i0; c < 64; c += 4) {
    float v = tile[j][c];  // W[r][f0+j][c0+c]
    unsigned short hi = f2bf(v);
    unsigned short* dst = Br + (size_t)(c0 + c) * 2 * F + f0 + j;
    dst[0] = hi; dst[F] = hi;
  }
}

// ---------- MFMA GEMM: C[r] = A2 @ B_cat[r]  (bf16 in, f32 acc) ----------
// 128x128 tile, BK=32, 4 waves of 64x64, fragment-ordered LDS (conflict-free).
// Depth-2 prefetch: 3 LDS buffers, counted vmcnt + raw s_barrier (T4-lite).
// Per iter each wave: wait vmcnt(4) lgkm(0) -> barrier -> issue 4 gload_lds
// for t+2 -> ds_read buf t -> 16 MFMA. vmcnt is in-order (m135), so
// vmcnt(4) with <=8 outstanding guarantees buffer t's 4 ops landed; lgkm(0)
// before the barrier guarantees prior-iter ds_reads drained LDS before any
// wave overwrites that buffer.
template <typename TC>
__global__ __launch_bounds__(256) void k_mgemm(const unsigned short* __restrict__ A2,
                                               const unsigned short* __restrict__ BT,
                                               TC* __restrict__ C, int Kp,
                                               long cstride) {
  const int bid = blockIdx.x;
  const int xcd = bid & 7;
  const int v = xcd * 500 + (bid >> 3);   // 4000 = 8 * 500, bijective
  const int mb = v >> 5;                  // m-panel, slowest
  const int nr = v & 31;                  // (n0, r) fastest
  const int n0 = (nr & 3) << 7;
  const int r = nr >> 2;

  const unsigned short* Br = BT + (size_t)r * 512 * Kp;
  TC* Cr = C + (size_t)r * cstride;
  const int m0 = mb * 128;
  __shared__ unsigned short Asm[3][4096];  // 8 fragment-groups * 512 shorts
  __shared__ unsigned short Bsm[3][4096];
  const int tid = threadIdx.x;
  const int wid = tid >> 6;
  const int lane = tid & 63;
  const int wr = wid >> 1, wc = wid & 1;
  const int rlow = lane & 15;
  const int kch = lane >> 4;  // k-chunk 0..3

  const unsigned short* gA0 = A2 + (size_t)(m0 + wid * 16 + rlow) * Kp + kch * 8;
  const unsigned short* gA1 = A2 + (size_t)(m0 + (wid + 4) * 16 + rlow) * Kp + kch * 8;
  const unsigned short* gB0 = Br + (size_t)(n0 + wid * 16 + rlow) * Kp + kch * 8;
  const unsigned short* gB1 = Br + (size_t)(n0 + (wid + 4) * 16 + rlow) * Kp + kch * 8;

  f32x4 acc[4][4] = {};
  const int nt = Kp >> 5;

  // prologue: stage buffers 0 and 1 (8 vm-ops per wave)
#pragma unroll
  for (int p = 0; p < 2; ++p) {
    const int k0 = p << 5;
    g2lds16(gA0 + k0, &Asm[p][wid * 512]);
    g2lds16(gA1 + k0, &Asm[p][(wid + 4) * 512]);
    g2lds16(gB0 + k0, &Bsm[p][wid * 512]);
    g2lds16(gB1 + k0, &Bsm[p][(wid + 4) * 512]);
  }

  int buf = 0;
  for (int t = 0; t < nt; ++t) {
    if (t + 1 < nt) {
      asm volatile("s_waitcnt vmcnt(4) lgkmcnt(0)" ::: "memory");
    } else {
      asm volatile("s_waitcnt vmcnt(0) lgkmcnt(0)" ::: "memory");
    }
    __builtin_amdgcn_s_barrier();
    asm volatile("" ::: "memory");
    if (t + 2 < nt) {
      const int k0 = (t + 2) << 5;
      int nb = buf + 2; if (nb >= 3) nb -= 3;
      g2lds16(gA0 + k0, &Asm[nb][wid * 512]);
      g2lds16(gA1 + k0, &Asm[nb][(wid + 4) * 512]);
      g2lds16(gB0 + k0, &Bsm[nb][wid * 512]);
      g2lds16(gB1 + k0, &Bsm[nb][(wid + 4) * 512]);
    }
    bf16x8 af[4], bfr[4];
#pragma unroll
    for (int i = 0; i < 4; ++i)
      af[i] = *(const bf16x8*)&Asm[buf][(wr * 4 + i) * 512 + lane * 8];
#pragma unroll
    for (int j = 0; j < 4; ++j)
      bfr[j] = *(const bf16x8*)&Bsm[buf][(wc * 4 + j) * 512 + lane * 8];
#pragma unroll
    for (int i = 0; i < 4; ++i)
#pragma unroll
      for (int j = 0; j < 4; ++j)
        acc[i][j] = __builtin_amdgcn_mfma_f32_16x16x32_bf16(af[i], bfr[j], acc[i][j],
                                                            0, 0, 0);
    buf = (buf == 2) ? 0 : buf + 1;
  }

  // epilogue: C/D layout col=lane&15, row=(lane>>4)*4+q  (guide m89)
#pragma unroll
  for (int i = 0; i < 4; ++i) {
    const int row0 = m0 + wr * 64 + i * 16 + kch * 4;
#pragma unroll
    for (int j = 0; j < 4; ++j) {
      const int col = n0 + wc * 64 + j * 16 + rlow;
#pragma unroll
      for (int q = 0; q < 4; ++q)
        storeC(&Cr[(size_t)(row0 + q) * HD + col], acc[i][j][q]);
    }
  }
}

// ---------- small fp32 GEMM (for qkbuf): C = A @ B, B:[F][128] ----------
__global__ __launch_bounds__(256) void k_gemm(const float* __restrict__ A,
                                              const float* __restrict__ B,
                                              float* __restrict__ C, int F) {
  const int m0 = blockIdx.x * 128;
  __shared__ float As[16][132];
  __shared__ float Bs[16][132];
  const int tid = threadIdx.x;
  const int arow = tid >> 2;
  const int acol = (tid & 3) << 2;
  const int brow = tid >> 5;
  const int bcol = (tid & 31) << 2;
  const int tr = ((tid >> 4) & 15) << 2;
  const int tc = (tid & 15) << 2;
  float acc[8][8] = {};
  for (int k0 = 0; k0 < F; k0 += 16) {
    float4 a0 = *(const float4*)&A[(size_t)(m0 + arow) * F + k0 + acol];
    float4 a1 = *(const float4*)&A[(size_t)(m0 + arow + 64) * F + k0 + acol];
    float4 b0 = *(const float4*)&B[(size_t)(k0 + brow) * 128 + bcol];
    float4 b1 = *(const float4*)&B[(size_t)(k0 + brow + 8) * 128 + bcol];
    As[acol + 0][arow] = a0.x; As[acol + 1][arow] = a0.y;
    As[acol + 2][arow] = a0.z; As[acol + 3][arow] = a0.w;
    As[acol + 0][arow + 64] = a1.x; As[acol + 1][arow + 64] = a1.y;
    As[acol + 2][arow + 64] = a1.z; As[acol + 3][arow + 64] = a1.w;
    *(float4*)&Bs[brow][bcol] = b0;
    *(float4*)&Bs[brow + 8][bcol] = b1;
    __syncthreads();
#pragma unroll
    for (int k = 0; k < 16; ++k) {
      float a[8], b[8];
      *(float4*)(a) = *(const float4*)&As[k][tr];
      *(float4*)(a + 4) = *(const float4*)&As[k][tr + 64];
      *(float4*)(b) = *(const float4*)&Bs[k][tc];
      *(float4*)(b + 4) = *(const float4*)&Bs[k][tc + 64];
#pragma unroll
      for (int i = 0; i < 8; ++i)
#pragma unroll
        for (int j = 0; j < 8; ++j)
          acc[i][j] = fmaf(a[i], b[j], acc[i][j]);
    }
    __syncthreads();
  }
#pragma unroll
  for (int i = 0; i < 8; ++i) {
    int row = m0 + tr + ((i < 4) ? i : (60 + i));
    *(float4*)&C[(size_t)row * 128 + tc] = make_float4(acc[i][0], acc[i][1], acc[i][2], acc[i][3]);
    *(float4*)&C[(size_t)row * 128 + tc + 64] = make_float4(acc[i][4], acc[i][5], acc[i][6], acc[i][7]);
  }
}

// ---------- fused attention + aggregation, one block per dst node ----------
template <typename T, int CONCAT>
__global__ __launch_bounds__(256) void k_attn(const T* __restrict__ t,
    const float* __restrict__ qkbuf, const float* __restrict__ cvec,
    const int* __restrict__ rowptr, const int* __restrict__ csr_src,
    const int* __restrict__ csr_et, const float* __restrict__ csr_ea,
    const float* __restrict__ bias, float* __restrict__ out) {
  const int n = blockIdx.x;
  const int tid = threadIdx.x;
  const int h = tid >> 5;  // head of elements 2*tid, 2*tid+1
  const int e0 = rowptr[n], e1 = rowptr[n + 1];
  const float ch = cvec[h];
  const float* qrow = qkbuf + (size_t)n * 128;
  float m = -1e30f, l = 0.f, acc0 = 0.f, acc1 = 0.f;
  for (int e = e0; e < e1; ++e) {
    int s = csr_src[e];
    int r = csr_et[e];
    float a = csr_ea[e];
    float logit = qrow[r * 16 + h]
                + qkbuf[(size_t)s * 128 + r * 16 + 8 + h] + a * ch;
    logit = (logit > 0.f) ? logit : NEG * logit;
    float mn = fmaxf(m, logit);
    float sc = __expf(m - mn);
    float p = __expf(logit - mn);
    float2 tv = load2(&t[((size_t)r * NN + s) * HD + 2 * tid]);
    l = l * sc + p;
    acc0 = acc0 * sc + p * tv.x;
    acc1 = acc1 * sc + p * tv.y;
    m = mn;
  }
  float inv = 1.f / (l + 1e-16f);
  float v0 = acc0 * inv, v1 = acc1 * inv;
  if (CONCAT) {
    float2 bb = *(const float2*)&bias[2 * tid];
    *(float2*)&out[(size_t)n * HD + 2 * tid] = make_float2(v0 + bb.x, v1 + bb.y);
  } else {
    __shared__ float sm[HD];
    sm[2 * tid] = v0; sm[2 * tid + 1] = v1;
    __syncthreads();
    if (tid < DOUT) {
      float s = 0.f;
#pragma unroll
      for (int hh = 0; hh < NHEAD; ++hh) s += sm[hh * DOUT + tid];
      out[(size_t)n * DOUT + tid] = s * 0.125f + bias[tid];
    }
  }
}

// ---------- launch ----------
template <typename TC>
static void run_pipeline(const float* x, const int* ei, const int* et, const float* ea,
                         const float* W1, const float* q1, const float* k1,
                         const float* We1, const float* e1, const float* b1,
                         const float* W2, const float* q2, const float* k2,
                         const float* We2, const float* e2, const float* b2,
                         float* out, float* hbuf, float* qkbuf, float* WQK,
                         unsigned short* A2, unsigned short* BT,
                         float* cvec, int* meta, int* deg, int* rowptr,
                         int* fill, int* csr_src, int* csr_et, float* csr_ea,
                         TC* t, hipStream_t stream) {
  (void)hipMemsetAsync(meta, 0, 4, stream);
  (void)hipMemsetAsync(deg, 0, (size_t)NN * 4, stream);
  k_max_et<<<EE / 256, 256, 0, stream>>>(et, meta);
  k_hist<<<(ETOT + 255) / 256, 256, 0, stream>>>(ei, deg);
  k_scan<<<1, 1024, 0, stream>>>(deg, rowptr, fill);
  k_scatter<<<(ETOT + 255) / 256, 256, 0, stream>>>(ei, et, ea, meta, fill,
                                                    csr_src, csr_et, csr_ea);
  // layer 1 (F=256, Kp=512)
  k_cvec<<<1, 64, 0, stream>>>(We1, e1, cvec);
  k_wqk<<<RREL * 256 * 16 / 256, 256, 0, stream>>>(W1, q1, k1, WQK, 256);
  k_asplit<<<(NN * 64 + 255) / 256, 256, 0, stream>>>(x, A2, 256);
  k_bsplit<<<dim3(4, 8, RREL), 256, 0, stream>>>(W1, BT, 256);
  k_mgemm<TC><<<4000, 256, 0, stream>>>(A2, BT, t, 512, (long)NN * HD);
  k_gemm<<<125, 256, 0, stream>>>(x, WQK, qkbuf, 256);
  k_attn<TC, 1><<<NN, 256, 0, stream>>>(t, qkbuf, cvec, rowptr, csr_src, csr_et,
                                        csr_ea, b1, hbuf);
  // layer 2 (F=512, Kp=1024)
  k_cvec<<<1, 64, 0, stream>>>(We2, e2, cvec);
  k_wqk<<<RREL * HD * 16 / 256, 256, 0, stream>>>(W2, q2, k2, WQK, HD);
  k_asplit<<<(NN * 128 + 255) / 256, 256, 0, stream>>>(hbuf, A2, HD);
  k_bsplit<<<dim3(8, 8, RREL), 256, 0, stream>>>(W2, BT, HD);
  k_mgemm<TC><<<4000, 256, 0, stream>>>(A2, BT, t, 1024, (long)NN * HD);
  k_gemm<<<125, 256, 0, stream>>>(hbuf, WQK, qkbuf, HD);
  k_attn<TC, 0><<<NN, 256, 0, stream>>>(t, qkbuf, cvec, rowptr, csr_src, csr_et,
                                        csr_ea, b2, out);
}

extern "C" void kernel_launch(void* const* d_in, const int* in_sizes, int n_in,
                              void* d_out, int out_size, void* d_ws, size_t ws_size,
                              hipStream_t stream) {
  const float* x   = (const float*)d_in[0];
  const int*   ei  = (const int*)d_in[1];
  const int*   et  = (const int*)d_in[2];
  const float* ea  = (const float*)d_in[3];
  const float* W1  = (const float*)d_in[4];
  const float* q1  = (const float*)d_in[5];
  const float* k1  = (const float*)d_in[6];
  const float* We1 = (const float*)d_in[7];
  const float* e1  = (const float*)d_in[8];
  const float* b1  = (const float*)d_in[9];
  const float* W2  = (const float*)d_in[10];
  const float* q2  = (const float*)d_in[11];
  const float* k2  = (const float*)d_in[12];
  const float* We2 = (const float*)d_in[13];
  const float* e2  = (const float*)d_in[14];
  const float* b2  = (const float*)d_in[15];
  float* out = (float*)d_out;

  char* w = (char*)d_ws;
  auto alloc = [&](size_t bytes) {
    char* p = w;
    w += (bytes + 255) & ~(size_t)255;
    return p;
  };
  float* hbuf   = (float*)alloc((size_t)NN * HD * 4);
  float* qkbuf  = (float*)alloc((size_t)NN * 128 * 4);
  float* WQK    = (float*)alloc((size_t)HD * 128 * 4);
  unsigned short* A2 = (unsigned short*)alloc((size_t)NN * 2 * HD * 2);
  unsigned short* BT = (unsigned short*)alloc((size_t)RREL * HD * 2 * HD * 2);
  float* cvec   = (float*)alloc(64);
  int*   meta   = (int*)alloc(64);
  int*   deg    = (int*)alloc((size_t)NN * 4);
  int*   rowptr = (int*)alloc((size_t)(NN + 1) * 4);
  int*   fill   = (int*)alloc((size_t)NN * 4);
  int*   csr_src= (int*)alloc((size_t)ETOT * 4);
  int*   csr_et = (int*)alloc((size_t)ETOT * 4);
  float* csr_ea = (float*)alloc((size_t)ETOT * 4);
  size_t used = (size_t)(w - (char*)d_ws);
  size_t t_elems = (size_t)RREL * NN * HD;

  if (used + t_elems * 4 <= ws_size) {
    float* t = (float*)w;
    run_pipeline<float>(x, ei, et, ea, W1, q1, k1, We1, e1, b1,
                        W2, q2, k2, We2, e2, b2, out, hbuf, qkbuf, WQK, A2, BT,
                        cvec, meta, deg, rowptr, fill, csr_src, csr_et, csr_ea,
                        t, stream);
  } else {
    unsigned short* t = (unsigned short*)w;
    run_pipeline<unsigned short>(x, ei, et, ea, W1, q1, k1, We1, e1, b1,
                                 W2, q2, k2, We2, e2, b2, out, hbuf, qkbuf, WQK,
                                 A2, BT, cvec, meta, deg, rowptr, fill, csr_src,
                                 csr_et, csr_ea, t, stream);
  }
}